// Round 1
// baseline (2028.474 us; speedup 1.0000x reference)
//
#include <hip/hip_runtime.h>
#include <math.h>

#define H 128
#define NGRAPH 64
#define TM 128
#define TK 32

// ---------------- setup: degree + per-node edge count ----------------
__global__ void k_deg_count(const int* __restrict__ col, const float* __restrict__ w,
                            float* __restrict__ deg, int* __restrict__ cnt, int E) {
  int e = blockIdx.x * blockDim.x + threadIdx.x;
  if (e < E) {
    int c = col[e];
    atomicAdd(&deg[c], w[e]);
    atomicAdd(&cnt[c], 1);
  }
}

// ---------------- exclusive scan of cnt -> ptr (CSC offsets) ----------------
__global__ __launch_bounds__(1024) void k_scan(const int* __restrict__ cnt,
                                               int* __restrict__ ptr,
                                               int* __restrict__ cursor, int N) {
  __shared__ int sums[1024];
  int t = threadIdx.x;
  int per = (N + 1023) >> 10;
  int start = t * per;
  int end = min(start + per, N);
  int s = 0;
  for (int i = start; i < end; i++) s += cnt[i];
  sums[t] = s;
  __syncthreads();
  for (int d = 1; d < 1024; d <<= 1) {
    int v = (t >= d) ? sums[t - d] : 0;
    __syncthreads();
    sums[t] += v;
    __syncthreads();
  }
  int run = sums[t] - s;  // exclusive prefix
  for (int i = start; i < end; i++) {
    ptr[i] = run;
    cursor[i] = run;
    run += cnt[i];
  }
  if (t == 1023) ptr[N] = sums[1023];
}

// ---------------- gcn_norm + scatter edges into CSC order ----------------
__global__ void k_norm_scatter(const int* __restrict__ row, const int* __restrict__ col,
                               const float* __restrict__ w, const float* __restrict__ deg,
                               int* __restrict__ cursor, int* __restrict__ rs,
                               float* __restrict__ ns, int E) {
  int e = blockIdx.x * blockDim.x + threadIdx.x;
  if (e < E) {
    int r = row[e], c = col[e];
    float dr = deg[r], dc = deg[c];
    float ir = dr > 0.f ? rsqrtf(dr) : 0.f;
    float ic = dc > 0.f ? rsqrtf(dc) : 0.f;
    float nm = ir * w[e] * ic;
    int pos = atomicAdd(&cursor[c], 1);
    rs[pos] = r;
    ns[pos] = nm;
  }
}

// ---------------- propagation: hout[v] = sum_e norm_e * hin[row_e] ----------------
// one 64-lane wave per destination node, 2 floats per lane
__global__ __launch_bounds__(256) void k_prop(const float* __restrict__ hin,
                                              float* __restrict__ hout,
                                              const int* __restrict__ ptr,
                                              const int* __restrict__ rs,
                                              const float* __restrict__ ns, int N) {
  int wid = (int)((blockIdx.x * (unsigned)blockDim.x + threadIdx.x) >> 6);
  if (wid >= N) return;
  int lane = threadIdx.x & 63;
  int s = ptr[wid], e = ptr[wid + 1];
  float ax = 0.f, ay = 0.f;
  const float* base = hin + (size_t)lane * 2;
  #pragma unroll 2
  for (int i = s; i < e; i++) {
    int r = rs[i];
    float nm = ns[i];
    const float2 v = *(const float2*)(base + (size_t)r * H);
    ax = fmaf(nm, v.x, ax);
    ay = fmaf(nm, v.y, ay);
  }
  float2 o;
  o.x = ax;
  o.y = ay;
  *(float2*)(hout + (size_t)wid * H + (size_t)lane * 2) = o;
}

// ---------------- fp32 GEMM: C (op)= A[N,128] @ B[128,128] ----------------
// MODE 0: C = A@B + bias ; MODE 1: C += A@B ; MODE 2: C = relu(C + A@B)
template <int MODE>
__global__ __launch_bounds__(256) void k_gemm(const float* __restrict__ A,
                                              const float* __restrict__ B,
                                              const float* __restrict__ bias,
                                              float* __restrict__ C, int N) {
  __shared__ float At[TK][TM + 4];  // transposed A chunk, pad 4 keeps 16B align, kills write conflicts
  __shared__ float Bs[TK][H];
  int t = threadIdx.x;
  int r0 = blockIdx.x * TM;
  int tr = t >> 4, tc = t & 15;
  int rr = tr * 8, cc = tc * 8;
  float acc[8][8];
  #pragma unroll
  for (int i = 0; i < 8; i++)
    #pragma unroll
    for (int j = 0; j < 8; j++) acc[i][j] = 0.f;

  for (int k0 = 0; k0 < H; k0 += TK) {
    #pragma unroll
    for (int i = 0; i < 4; i++) {
      int idx = t + i * 256;        // 0..1023 float4 slots of B chunk
      int bk = idx >> 5;            // 0..31
      int bj = (idx & 31) << 2;     // 0..124
      *(float4*)&Bs[bk][bj] = *(const float4*)&B[(size_t)(k0 + bk) * H + bj];
    }
    #pragma unroll
    for (int i = 0; i < 4; i++) {
      int idx = t + i * 256;        // 0..1023 float4 slots of A chunk
      int ar = idx >> 3;            // 0..127
      int as = (idx & 7) << 2;      // 0..28
      int gr = r0 + ar;
      float4 v = make_float4(0.f, 0.f, 0.f, 0.f);
      if (gr < N) v = *(const float4*)&A[(size_t)gr * H + k0 + as];
      At[as + 0][ar] = v.x;
      At[as + 1][ar] = v.y;
      At[as + 2][ar] = v.z;
      At[as + 3][ar] = v.w;
    }
    __syncthreads();
    #pragma unroll
    for (int k = 0; k < TK; k++) {
      float a[8], b[8];
      *(float4*)&a[0] = *(const float4*)&At[k][rr];
      *(float4*)&a[4] = *(const float4*)&At[k][rr + 4];
      *(float4*)&b[0] = *(const float4*)&Bs[k][cc];
      *(float4*)&b[4] = *(const float4*)&Bs[k][cc + 4];
      #pragma unroll
      for (int i = 0; i < 8; i++)
        #pragma unroll
        for (int j = 0; j < 8; j++) acc[i][j] = fmaf(a[i], b[j], acc[i][j]);
    }
    __syncthreads();
  }

  #pragma unroll
  for (int i = 0; i < 8; i++) {
    int r = r0 + rr + i;
    if (r >= N) continue;
    #pragma unroll
    for (int j = 0; j < 8; j += 4) {
      int colj = cc + j;
      float4 v = make_float4(acc[i][j], acc[i][j + 1], acc[i][j + 2], acc[i][j + 3]);
      if (MODE == 0) {
        const float4 bb = *(const float4*)&bias[colj];
        v.x += bb.x; v.y += bb.y; v.z += bb.z; v.w += bb.w;
      } else {
        const float4 c4 = *(const float4*)&C[(size_t)r * H + colj];
        v.x += c4.x; v.y += c4.y; v.z += c4.z; v.w += c4.w;
        if (MODE == 2) {
          v.x = fmaxf(v.x, 0.f); v.y = fmaxf(v.y, 0.f);
          v.z = fmaxf(v.z, 0.f); v.w = fmaxf(v.w, 0.f);
        }
      }
      *(float4*)&C[(size_t)r * H + colj] = v;
    }
  }
}

// ---------------- graph boundaries from sorted batch ----------------
__global__ void k_bounds(const int* __restrict__ batch, int* __restrict__ gstart, int N) {
  int g = threadIdx.x;
  if (g > NGRAPH) return;
  int lo = 0, hi = N;
  while (lo < hi) {
    int mid = (lo + hi) >> 1;
    if (batch[mid] < g) lo = mid + 1;
    else hi = mid;
  }
  gstart[g] = lo;
}

// ---------------- global mean pool ----------------
__global__ __launch_bounds__(128) void k_pool(const float* __restrict__ h,
                                              const int* __restrict__ gstart,
                                              float* __restrict__ pooled) {
  int g = blockIdx.x;
  int j = threadIdx.x;
  int s = gstart[g], e = gstart[g + 1];
  float acc = 0.f;
  for (int i = s; i < e; i++) acc += h[(size_t)i * H + j];
  float c = (float)max(e - s, 1);
  pooled[g * H + j] = acc / c;
}

// ---------------- head: sigmoid((pool @ W1 + b1) @ W2 + b2) ----------------
__global__ __launch_bounds__(128) void k_head(const float* __restrict__ pooled,
                                              const float* __restrict__ w1,
                                              const float* __restrict__ b1,
                                              const float* __restrict__ w2,
                                              const float* __restrict__ b2,
                                              float* __restrict__ out) {
  int g = blockIdx.x;
  int j = threadIdx.x;
  __shared__ float pv[H];
  __shared__ float red[H];
  pv[j] = pooled[g * H + j];
  __syncthreads();
  float t1 = b1[j];
  #pragma unroll 4
  for (int k = 0; k < H; k++) t1 = fmaf(pv[k], w1[k * H + j], t1);
  red[j] = t1 * w2[j];
  __syncthreads();
  if (j < 64) {
    float s = red[j] + red[j + 64];
    #pragma unroll
    for (int o = 32; o; o >>= 1) s += __shfl_down(s, o);
    if (j == 0) out[g] = 1.f / (1.f + expf(-(s + b2[0])));
  }
}

extern "C" void kernel_launch(void* const* d_in, const int* in_sizes, int n_in,
                              void* d_out, int out_size, void* d_ws, size_t ws_size,
                              hipStream_t stream) {
  const float* x = (const float*)d_in[0];
  const int* eidx = (const int*)d_in[1];
  const float* ew = (const float*)d_in[2];
  const int* batch = (const int*)d_in[3];
  const float* conv_ws = (const float*)d_in[4];  // [5][4][128][128]
  const float* conv_bs = (const float*)d_in[5];  // [5][128]
  const float* lin1_w = (const float*)d_in[6];
  const float* lin1_b = (const float*)d_in[7];
  const float* lin2_w = (const float*)d_in[8];
  const float* lin2_b = (const float*)d_in[9];
  float* out = (float*)d_out;

  const int N = in_sizes[0] / H;  // 50000
  const int E = in_sizes[2];      // 800000
  const int* row = eidx;
  const int* col = eidx + E;

  // workspace carve (~85 MB total)
  char* p = (char*)d_ws;
  auto alloc = [&](size_t bytes) {
    char* q = p;
    p += (bytes + 255) & ~(size_t)255;
    return q;
  };
  float* deg = (float*)alloc((size_t)N * 4);
  int* cnt = (int*)alloc((size_t)N * 4);
  int* ptrb = (int*)alloc((size_t)(N + 1) * 4);
  int* cursor = (int*)alloc((size_t)N * 4);
  int* rs = (int*)alloc((size_t)E * 4);
  float* ns = (float*)alloc((size_t)E * 4);
  float* bufA = (float*)alloc((size_t)N * H * 4);
  float* bufB = (float*)alloc((size_t)N * H * 4);
  float* bufC = (float*)alloc((size_t)N * H * 4);
  int* gstart = (int*)alloc((NGRAPH + 1) * 4);
  float* pooled = (float*)alloc((size_t)NGRAPH * H * 4);

  hipMemsetAsync(deg, 0, (size_t)N * 4, stream);
  hipMemsetAsync(cnt, 0, (size_t)N * 4, stream);

  int eb = (E + 255) / 256;
  k_deg_count<<<eb, 256, 0, stream>>>(col, ew, deg, cnt, E);
  k_scan<<<1, 1024, 0, stream>>>(cnt, ptrb, cursor, N);
  k_norm_scatter<<<eb, 256, 0, stream>>>(row, col, ew, deg, cursor, rs, ns, E);

  int gemm_blocks = (N + TM - 1) / TM;
  int prop_blocks = (N + 3) / 4;  // 4 waves (=4 nodes) per 256-thread block

  // buffer rotation: 3 buffers suffice for {out, prop ping, prop pong}
  const float* P = x;      // layer input
  float* Q = bufA;         // layer output accumulator
  float* R = bufB;         // prop ping
  float* S = bufC;         // prop pong (layer 0 only; later reuses P's buffer)

  for (int layer = 0; layer < 5; layer++) {
    const float* W = conv_ws + (size_t)layer * 4 * H * H;
    const float* b = conv_bs + (size_t)layer * H;
    float* T = (layer == 0) ? S : (float*)P;  // P consumed before T is written

    k_gemm<0><<<gemm_blocks, 256, 0, stream>>>(P, W + 0 * H * H, b, Q, N);
    k_prop<<<prop_blocks, 256, 0, stream>>>(P, R, ptrb, rs, ns, N);
    k_gemm<1><<<gemm_blocks, 256, 0, stream>>>(R, W + 1 * H * H, nullptr, Q, N);
    k_prop<<<prop_blocks, 256, 0, stream>>>(R, T, ptrb, rs, ns, N);
    k_gemm<1><<<gemm_blocks, 256, 0, stream>>>(T, W + 2 * H * H, nullptr, Q, N);
    k_prop<<<prop_blocks, 256, 0, stream>>>(T, R, ptrb, rs, ns, N);
    k_gemm<2><<<gemm_blocks, 256, 0, stream>>>(R, W + 3 * H * H, nullptr, Q, N);

    // rotate: new input is Q; T and R become the scratch pair
    const float* newP = Q;
    Q = T;
    P = newP;
    // R stays R
  }

  k_bounds<<<1, 128, 0, stream>>>(batch, gstart, N);
  k_pool<<<NGRAPH, 128, 0, stream>>>((const float*)P, gstart, pooled);
  k_head<<<NGRAPH, 128, 0, stream>>>(pooled, lin1_w, lin1_b, lin2_w, lin2_b, out);
}

// Round 2
// 1160.622 us; speedup vs baseline: 1.7477x; 1.7477x over previous
//
#include <hip/hip_runtime.h>
#include <math.h>

#define H 128
#define NGRAPH 64

using short8 = __attribute__((ext_vector_type(8))) short;
using f32x4 = __attribute__((ext_vector_type(4))) float;

__device__ inline float bf2f(ushort u) {
  unsigned int b = ((unsigned int)u) << 16;
  return __builtin_bit_cast(float, b);
}
__device__ inline ushort f2bf(float f) {
  unsigned int u = __builtin_bit_cast(unsigned int, f);
  u = (u + 0x7FFF + ((u >> 16) & 1)) >> 16;  // RNE
  return (ushort)u;
}

// ---------------- x fp32 -> bf16 ----------------
__global__ __launch_bounds__(256) void k_cvt_x(const float* __restrict__ x,
                                               ushort* __restrict__ xb, int total4) {
  int i = blockIdx.x * blockDim.x + threadIdx.x;
  if (i >= total4) return;
  float4 v = *(const float4*)(x + (size_t)i * 4);
  ushort4 o;
  o.x = f2bf(v.x); o.y = f2bf(v.y); o.z = f2bf(v.z); o.w = f2bf(v.w);
  *(ushort4*)(xb + (size_t)i * 4) = o;
}

// ---------------- transpose+convert weights: Wt[l][j][k] = W[l][k/128][k%128][j] ----------------
__global__ __launch_bounds__(256) void k_cvt_w(const float* __restrict__ w,
                                               ushort* __restrict__ wt, int total) {
  int i = blockIdx.x * blockDim.x + threadIdx.x;
  if (i >= total) return;           // total = 5*128*512
  int l = i >> 16;                  // /65536
  int rem = i & 65535;
  int j = rem >> 9;                 // 0..127
  int k = rem & 511;                // 0..511
  int q = k >> 7, kk = k & 127;
  float v = w[(((size_t)l * 4 + q) * H + kk) * H + j];
  wt[i] = f2bf(v);
}

// ---------------- setup: degree + per-node edge count ----------------
__global__ void k_deg_count(const int* __restrict__ col, const float* __restrict__ w,
                            float* __restrict__ deg, int* __restrict__ cnt, int E) {
  int e = blockIdx.x * blockDim.x + threadIdx.x;
  if (e < E) {
    int c = col[e];
    atomicAdd(&deg[c], w[e]);
    atomicAdd(&cnt[c], 1);
  }
}

// ---------------- exclusive scan of cnt -> ptr (CSC offsets) ----------------
__global__ __launch_bounds__(1024) void k_scan(const int* __restrict__ cnt,
                                               int* __restrict__ ptr,
                                               int* __restrict__ cursor, int N) {
  __shared__ int sums[1024];
  int t = threadIdx.x;
  int per = (N + 1023) >> 10;
  int start = t * per;
  int end = min(start + per, N);
  int s = 0;
  for (int i = start; i < end; i++) s += cnt[i];
  sums[t] = s;
  __syncthreads();
  for (int d = 1; d < 1024; d <<= 1) {
    int v = (t >= d) ? sums[t - d] : 0;
    __syncthreads();
    sums[t] += v;
    __syncthreads();
  }
  int run = sums[t] - s;  // exclusive prefix
  for (int i = start; i < end; i++) {
    ptr[i] = run;
    cursor[i] = run;
    run += cnt[i];
  }
  if (t == 1023) ptr[N] = sums[1023];
}

// ---------------- gcn_norm + scatter edges into CSC order ----------------
__global__ void k_norm_scatter(const int* __restrict__ row, const int* __restrict__ col,
                               const float* __restrict__ w, const float* __restrict__ deg,
                               int* __restrict__ cursor, int* __restrict__ rs,
                               float* __restrict__ ns, int E) {
  int e = blockIdx.x * blockDim.x + threadIdx.x;
  if (e < E) {
    int r = row[e], c = col[e];
    float dr = deg[r], dc = deg[c];
    float ir = dr > 0.f ? rsqrtf(dr) : 0.f;
    float ic = dc > 0.f ? rsqrtf(dc) : 0.f;
    float nm = ir * w[e] * ic;
    int pos = atomicAdd(&cursor[c], 1);
    rs[pos] = r;
    ns[pos] = nm;
  }
}

// ---------------- propagation (bf16 in/out): hout[v] = sum_e norm_e * hin[row_e] ----------------
// one 64-lane wave per destination node, 2 bf16 per lane
__global__ __launch_bounds__(256) void k_prop(const ushort* __restrict__ hin,
                                              ushort* __restrict__ hout,
                                              const int* __restrict__ ptr,
                                              const int* __restrict__ rs,
                                              const float* __restrict__ ns, int N) {
  int wid = (int)((blockIdx.x * (unsigned)blockDim.x + threadIdx.x) >> 6);
  if (wid >= N) return;
  int lane = threadIdx.x & 63;
  int s = ptr[wid], e = ptr[wid + 1];
  float ax = 0.f, ay = 0.f;
  const ushort* base = hin + lane * 2;
  #pragma unroll 2
  for (int i = s; i < e; i++) {
    int r = rs[i];
    float nm = ns[i];
    unsigned int v = *(const unsigned int*)(base + (size_t)r * H);
    float vx = __builtin_bit_cast(float, v << 16);
    float vy = __builtin_bit_cast(float, v & 0xFFFF0000u);
    ax = fmaf(nm, vx, ax);
    ay = fmaf(nm, vy, ay);
  }
  unsigned int o = (unsigned int)f2bf(ax) | ((unsigned int)f2bf(ay) << 16);
  *(unsigned int*)(hout + (size_t)wid * H + lane * 2) = o;
}

// ---------------- fused TAGConv GEMM: O = relu([X0|X1|X2|X3] @ Wcat + b) ----------------
// bf16 inputs, fp32 MFMA accumulate, bf16 output. Block: 128 rows x 128 cols, 4 waves (2x2).
__global__ __launch_bounds__(256) void k_fgemm(const ushort* __restrict__ X0,
                                               const ushort* __restrict__ X1,
                                               const ushort* __restrict__ X2,
                                               const ushort* __restrict__ X3,
                                               const ushort* __restrict__ Wt,  // [128][512] bf16 (j-major)
                                               const float* __restrict__ bias,
                                               ushort* __restrict__ O, int N) {
  __shared__ ushort As[128][72];  // [row][k] pad 8 -> stride 144B (16B-aligned, ~2-way banks)
  __shared__ ushort Bs[128][72];  // [col j][k]
  int t = threadIdx.x;
  int r0 = blockIdx.x * 128;
  int w = t >> 6, lane = t & 63;
  int mw = w >> 1, nw = w & 1;
  int l15 = lane & 15, l4 = lane >> 4;

  f32x4 acc[4][4];
  #pragma unroll
  for (int i = 0; i < 4; i++)
    #pragma unroll
    for (int j = 0; j < 4; j++) acc[i][j] = (f32x4){0.f, 0.f, 0.f, 0.f};

  for (int it = 0; it < 8; ++it) {
    const ushort* Xp = (it < 2) ? X0 : (it < 4) ? X1 : (it < 6) ? X2 : X3;
    int kb = (it & 1) * 64;  // column offset within Xp
    int k0 = it * 64;        // column offset within Wt rows
    // stage A (128x64 bf16) and B (128x64 bf16), 16B per thread per pass
    #pragma unroll
    for (int p = 0; p < 4; p++) {
      int idx = t + p * 256;          // 0..1023
      int rj = idx >> 3;              // 0..127
      int kc = (idx & 7) << 3;        // 0..56
      int gr = r0 + rj;
      short8 av = (short8){0,0,0,0,0,0,0,0};
      if (gr < N) av = *(const short8*)(Xp + (size_t)gr * H + kb + kc);
      *(short8*)&As[rj][kc] = av;
      *(short8*)&Bs[rj][kc] = *(const short8*)(Wt + (size_t)rj * 512 + k0 + kc);
    }
    __syncthreads();
    #pragma unroll
    for (int ks = 0; ks < 2; ks++) {
      int kk = ks * 32 + l4 * 8;
      short8 a[4], b[4];
      #pragma unroll
      for (int mf = 0; mf < 4; mf++) a[mf] = *(const short8*)&As[mw * 64 + mf * 16 + l15][kk];
      #pragma unroll
      for (int nf = 0; nf < 4; nf++) b[nf] = *(const short8*)&Bs[nw * 64 + nf * 16 + l15][kk];
      #pragma unroll
      for (int mf = 0; mf < 4; mf++)
        #pragma unroll
        for (int nf = 0; nf < 4; nf++)
          acc[mf][nf] = __builtin_amdgcn_mfma_f32_16x16x32_bf16(a[mf], b[nf], acc[mf][nf], 0, 0, 0);
    }
    __syncthreads();
  }

  // epilogue: bias + relu + bf16 store.  row = r0+mw*64+mf*16+l4*4+r, col = nw*64+nf*16+l15
  #pragma unroll
  for (int nf = 0; nf < 4; nf++) {
    int colj = nw * 64 + nf * 16 + l15;
    float bv = bias[colj];
    #pragma unroll
    for (int mf = 0; mf < 4; mf++) {
      int rbase = r0 + mw * 64 + mf * 16 + l4 * 4;
      #pragma unroll
      for (int r = 0; r < 4; r++) {
        int rr = rbase + r;
        if (rr < N) {
          float v = acc[mf][nf][r] + bv;
          v = fmaxf(v, 0.f);
          O[(size_t)rr * H + colj] = f2bf(v);
        }
      }
    }
  }
}

// ---------------- graph boundaries from sorted batch ----------------
__global__ void k_bounds(const int* __restrict__ batch, int* __restrict__ gstart, int N) {
  int g = threadIdx.x;
  if (g > NGRAPH) return;
  int lo = 0, hi = N;
  while (lo < hi) {
    int mid = (lo + hi) >> 1;
    if (batch[mid] < g) lo = mid + 1;
    else hi = mid;
  }
  gstart[g] = lo;
}

// ---------------- global mean pool: parallel atomic sums ----------------
#define POOL_ROWS 64
__global__ __launch_bounds__(256) void k_pool(const ushort* __restrict__ h,
                                              const int* __restrict__ batch,
                                              float* __restrict__ pooled, int N) {
  int r0 = blockIdx.x * POOL_ROWS;
  int j = threadIdx.x & 127;
  int half = threadIdx.x >> 7;
  int rend = min(r0 + POOL_ROWS, N);
  float acc = 0.f;
  int cur = -1;
  for (int r = r0 + half; r < rend; r += 2) {
    int g = batch[r];
    if (g != cur) {
      if (cur >= 0) atomicAdd(&pooled[cur * H + j], acc);
      cur = g;
      acc = 0.f;
    }
    acc += bf2f(h[(size_t)r * H + j]);
  }
  if (cur >= 0) atomicAdd(&pooled[cur * H + j], acc);
}

// ---------------- head: sigmoid((mean @ W1 + b1) @ W2 + b2) ----------------
__global__ __launch_bounds__(128) void k_head(const float* __restrict__ pooled,
                                              const int* __restrict__ gstart,
                                              const float* __restrict__ w1,
                                              const float* __restrict__ b1,
                                              const float* __restrict__ w2,
                                              const float* __restrict__ b2,
                                              float* __restrict__ out) {
  int g = blockIdx.x;
  int j = threadIdx.x;
  __shared__ float pv[H];
  __shared__ float red[H];
  float c = (float)max(gstart[g + 1] - gstart[g], 1);
  pv[j] = pooled[g * H + j] / c;
  __syncthreads();
  float t1 = b1[j];
  #pragma unroll 4
  for (int k = 0; k < H; k++) t1 = fmaf(pv[k], w1[k * H + j], t1);
  red[j] = t1 * w2[j];
  __syncthreads();
  if (j < 64) {
    float s = red[j] + red[j + 64];
    #pragma unroll
    for (int o = 32; o; o >>= 1) s += __shfl_down(s, o);
    if (j == 0) out[g] = 1.f / (1.f + expf(-(s + b2[0])));
  }
}

extern "C" void kernel_launch(void* const* d_in, const int* in_sizes, int n_in,
                              void* d_out, int out_size, void* d_ws, size_t ws_size,
                              hipStream_t stream) {
  const float* x = (const float*)d_in[0];
  const int* eidx = (const int*)d_in[1];
  const float* ew = (const float*)d_in[2];
  const int* batch = (const int*)d_in[3];
  const float* conv_ws = (const float*)d_in[4];  // [5][4][128][128]
  const float* conv_bs = (const float*)d_in[5];  // [5][128]
  const float* lin1_w = (const float*)d_in[6];
  const float* lin1_b = (const float*)d_in[7];
  const float* lin2_w = (const float*)d_in[8];
  const float* lin2_b = (const float*)d_in[9];
  float* out = (float*)d_out;

  const int N = in_sizes[0] / H;  // 50000
  const int E = in_sizes[2];      // 800000
  const int* row = eidx;
  const int* col = eidx + E;

  char* p = (char*)d_ws;
  auto alloc = [&](size_t bytes) {
    char* q = p;
    p += (bytes + 255) & ~(size_t)255;
    return q;
  };
  float* deg = (float*)alloc((size_t)N * 4);
  int* cnt = (int*)alloc((size_t)N * 4);
  int* ptrb = (int*)alloc((size_t)(N + 1) * 4);
  int* cursor = (int*)alloc((size_t)N * 4);
  int* rs = (int*)alloc((size_t)E * 4);
  float* ns = (float*)alloc((size_t)E * 4);
  ushort* xb = (ushort*)alloc((size_t)N * H * 2);
  ushort* B0 = (ushort*)alloc((size_t)N * H * 2);
  ushort* B1 = (ushort*)alloc((size_t)N * H * 2);
  ushort* B2 = (ushort*)alloc((size_t)N * H * 2);
  ushort* B3 = (ushort*)alloc((size_t)N * H * 2);
  ushort* Wt = (ushort*)alloc((size_t)5 * H * 512 * 2);
  int* gstart = (int*)alloc((NGRAPH + 1) * 4);
  float* pooled = (float*)alloc((size_t)NGRAPH * H * 4);

  hipMemsetAsync(deg, 0, (size_t)N * 4, stream);
  hipMemsetAsync(cnt, 0, (size_t)N * 4, stream);
  hipMemsetAsync(pooled, 0, (size_t)NGRAPH * H * 4, stream);

  int eb = (E + 255) / 256;
  k_cvt_x<<<(N * H / 4 + 255) / 256, 256, 0, stream>>>(x, xb, N * H / 4);
  k_cvt_w<<<(5 * H * 512 + 255) / 256, 256, 0, stream>>>(conv_ws, Wt, 5 * H * 512);
  k_deg_count<<<eb, 256, 0, stream>>>(col, ew, deg, cnt, E);
  k_scan<<<1, 1024, 0, stream>>>(cnt, ptrb, cursor, N);
  k_norm_scatter<<<eb, 256, 0, stream>>>(row, col, ew, deg, cursor, rs, ns, E);

  int gemm_blocks = (N + 127) / 128;
  int prop_blocks = (N + 3) / 4;  // 4 waves (nodes) per 256-thread block

  const ushort* P = xb;
  for (int layer = 0; layer < 5; layer++) {
    const ushort* Wl = Wt + (size_t)layer * H * 512;
    const float* bl = conv_bs + (size_t)layer * H;
    k_prop<<<prop_blocks, 256, 0, stream>>>(P, B0, ptrb, rs, ns, N);
    k_prop<<<prop_blocks, 256, 0, stream>>>(B0, B1, ptrb, rs, ns, N);
    k_prop<<<prop_blocks, 256, 0, stream>>>(B1, B2, ptrb, rs, ns, N);
    // O=B3 aliases P for layers>=1: each block writes only its own rows, after
    // its last read of those rows -> safe.
    k_fgemm<<<gemm_blocks, 256, 0, stream>>>(P, B0, B1, B2, Wl, bl, B3, N);
    P = B3;
  }

  k_bounds<<<1, 128, 0, stream>>>(batch, gstart, N);
  k_pool<<<(N + POOL_ROWS - 1) / POOL_ROWS, 256, 0, stream>>>(P, batch, pooled, N);
  k_head<<<NGRAPH, 128, 0, stream>>>(pooled, gstart, lin1_w, lin1_b, lin2_w, lin2_b, out);
}

// Round 3
// 858.360 us; speedup vs baseline: 2.3632x; 1.3521x over previous
//
#include <hip/hip_runtime.h>
#include <math.h>

#define H 128
#define NGRAPH 64

using short8 = __attribute__((ext_vector_type(8))) short;
using f32x4 = __attribute__((ext_vector_type(4))) float;

__device__ inline float bf2f(ushort u) {
  unsigned int b = ((unsigned int)u) << 16;
  return __builtin_bit_cast(float, b);
}
__device__ inline ushort f2bf(float f) {
  unsigned int u = __builtin_bit_cast(unsigned int, f);
  u = (u + 0x7FFF + ((u >> 16) & 1)) >> 16;  // RNE
  return (ushort)u;
}

// ---------------- x fp32 -> bf16 ----------------
__global__ __launch_bounds__(256) void k_cvt_x(const float* __restrict__ x,
                                               ushort* __restrict__ xb, int total4) {
  int i = blockIdx.x * blockDim.x + threadIdx.x;
  if (i >= total4) return;
  float4 v = *(const float4*)(x + (size_t)i * 4);
  ushort4 o;
  o.x = f2bf(v.x); o.y = f2bf(v.y); o.z = f2bf(v.z); o.w = f2bf(v.w);
  *(ushort4*)(xb + (size_t)i * 4) = o;
}

// ---------------- transpose+convert weights: Wt[l][j][k] = W[l][k/128][k%128][j] ----------------
__global__ __launch_bounds__(256) void k_cvt_w(const float* __restrict__ w,
                                               ushort* __restrict__ wt, int total) {
  int i = blockIdx.x * blockDim.x + threadIdx.x;
  if (i >= total) return;           // total = 5*128*512
  int l = i >> 16;                  // /65536
  int rem = i & 65535;
  int j = rem >> 9;                 // 0..127
  int k = rem & 511;                // 0..511
  int q = k >> 7, kk = k & 127;
  float v = w[(((size_t)l * 4 + q) * H + kk) * H + j];
  wt[i] = f2bf(v);
}

// ---------------- setup: degree + per-node edge count ----------------
__global__ void k_deg_count(const int* __restrict__ col, const float* __restrict__ w,
                            float* __restrict__ deg, int* __restrict__ cnt, int E) {
  int e = blockIdx.x * blockDim.x + threadIdx.x;
  if (e < E) {
    int c = col[e];
    atomicAdd(&deg[c], w[e]);
    atomicAdd(&cnt[c], 1);
  }
}

// ---------------- parallel 3-phase exclusive scan ----------------
// phase 1: per-block (256-wide) reduction of cnt
__global__ __launch_bounds__(256) void k_scan1(const int* __restrict__ cnt,
                                               int* __restrict__ bsum, int N) {
  int i = blockIdx.x * 256 + threadIdx.x;
  int v = (i < N) ? cnt[i] : 0;
  __shared__ int red[256];
  red[threadIdx.x] = v;
  __syncthreads();
  #pragma unroll
  for (int o = 128; o; o >>= 1) {
    if (threadIdx.x < o) red[threadIdx.x] += red[threadIdx.x + o];
    __syncthreads();
  }
  if (threadIdx.x == 0) bsum[blockIdx.x] = red[0];
}

// phase 2: single-block exclusive scan of block sums (nb <= 256)
__global__ __launch_bounds__(256) void k_scan2(const int* __restrict__ bsum,
                                               int* __restrict__ boff, int nb) {
  __shared__ int s[256];
  int t = threadIdx.x;
  int v = (t < nb) ? bsum[t] : 0;
  s[t] = v;
  __syncthreads();
  #pragma unroll
  for (int d = 1; d < 256; d <<= 1) {
    int u = (t >= d) ? s[t - d] : 0;
    __syncthreads();
    s[t] += u;
    __syncthreads();
  }
  if (t < nb) boff[t] = s[t] - v;  // exclusive prefix
}

// phase 3: per-block exclusive scan + global offset -> ptr, cursor
__global__ __launch_bounds__(256) void k_scan3(const int* __restrict__ cnt,
                                               const int* __restrict__ boff,
                                               int* __restrict__ ptr,
                                               int* __restrict__ cursor, int N) {
  int t = threadIdx.x;
  int i = blockIdx.x * 256 + t;
  int v = (i < N) ? cnt[i] : 0;
  __shared__ int s[256];
  s[t] = v;
  __syncthreads();
  #pragma unroll
  for (int d = 1; d < 256; d <<= 1) {
    int u = (t >= d) ? s[t - d] : 0;
    __syncthreads();
    s[t] += u;
    __syncthreads();
  }
  int ex = boff[blockIdx.x] + s[t] - v;
  if (i < N) {
    ptr[i] = ex;
    cursor[i] = ex;
    if (i == N - 1) ptr[N] = ex + v;
  }
}

// ---------------- gcn_norm + scatter packed edges into CSC order ----------------
__global__ void k_norm_scatter(const int* __restrict__ row, const int* __restrict__ col,
                               const float* __restrict__ w, const float* __restrict__ deg,
                               int* __restrict__ cursor, int2* __restrict__ es, int E) {
  int e = blockIdx.x * blockDim.x + threadIdx.x;
  if (e < E) {
    int r = row[e], c = col[e];
    float dr = deg[r], dc = deg[c];
    float ir = dr > 0.f ? rsqrtf(dr) : 0.f;
    float ic = dc > 0.f ? rsqrtf(dc) : 0.f;
    float nm = ir * w[e] * ic;
    int pos = atomicAdd(&cursor[c], 1);
    int2 pk;
    pk.x = r;
    pk.y = __builtin_bit_cast(int, nm);
    es[pos] = pk;
  }
}

// ---------------- propagation (bf16 in/out): hout[v] = sum_e norm_e * hin[row_e] ----------------
// one 64-lane wave per destination node, 2 bf16 per lane; edge data via scalar loads
__global__ __launch_bounds__(256) void k_prop(const ushort* __restrict__ hin,
                                              ushort* __restrict__ hout,
                                              const int* __restrict__ ptr,
                                              const int2* __restrict__ es, int N) {
  int wid = (int)((blockIdx.x * (unsigned)blockDim.x + threadIdx.x) >> 6);
  wid = __builtin_amdgcn_readfirstlane(wid);  // wave-uniform -> scalar loads below
  if (wid >= N) return;
  int lane = threadIdx.x & 63;
  int s = ptr[wid], e = ptr[wid + 1];
  float ax = 0.f, ay = 0.f, bx = 0.f, by = 0.f;
  const ushort* base = hin + lane * 2;
  int i = s;
  for (; i + 1 < e; i += 2) {
    int2 e0 = es[i];
    int2 e1 = es[i + 1];
    unsigned int v0 = *(const unsigned int*)(base + (size_t)e0.x * H);
    unsigned int v1 = *(const unsigned int*)(base + (size_t)e1.x * H);
    float n0 = __builtin_bit_cast(float, e0.y);
    float n1 = __builtin_bit_cast(float, e1.y);
    ax = fmaf(n0, __builtin_bit_cast(float, v0 << 16), ax);
    ay = fmaf(n0, __builtin_bit_cast(float, v0 & 0xFFFF0000u), ay);
    bx = fmaf(n1, __builtin_bit_cast(float, v1 << 16), bx);
    by = fmaf(n1, __builtin_bit_cast(float, v1 & 0xFFFF0000u), by);
  }
  if (i < e) {
    int2 e0 = es[i];
    unsigned int v0 = *(const unsigned int*)(base + (size_t)e0.x * H);
    float n0 = __builtin_bit_cast(float, e0.y);
    ax = fmaf(n0, __builtin_bit_cast(float, v0 << 16), ax);
    ay = fmaf(n0, __builtin_bit_cast(float, v0 & 0xFFFF0000u), ay);
  }
  ax += bx;
  ay += by;
  unsigned int o = (unsigned int)f2bf(ax) | ((unsigned int)f2bf(ay) << 16);
  *(unsigned int*)(hout + (size_t)wid * H + lane * 2) = o;
}

// ---------------- fused TAGConv GEMM: O = relu([X0|X1|X2|X3] @ Wcat + b) ----------------
// bf16 inputs, fp32 MFMA accumulate, bf16 output. Block: 128 rows x 128 cols, 4 waves (2x2).
__global__ __launch_bounds__(256) void k_fgemm(const ushort* __restrict__ X0,
                                               const ushort* __restrict__ X1,
                                               const ushort* __restrict__ X2,
                                               const ushort* __restrict__ X3,
                                               const ushort* __restrict__ Wt,  // [128][512] bf16 (j-major)
                                               const float* __restrict__ bias,
                                               ushort* __restrict__ O, int N) {
  __shared__ ushort As[128][72];  // [row][k] pad 8 -> stride 144B (16B-aligned, ~2-way banks)
  __shared__ ushort Bs[128][72];  // [col j][k]
  int t = threadIdx.x;
  int r0 = blockIdx.x * 128;
  int w = t >> 6, lane = t & 63;
  int mw = w >> 1, nw = w & 1;
  int l15 = lane & 15, l4 = lane >> 4;

  f32x4 acc[4][4];
  #pragma unroll
  for (int i = 0; i < 4; i++)
    #pragma unroll
    for (int j = 0; j < 4; j++) acc[i][j] = (f32x4){0.f, 0.f, 0.f, 0.f};

  for (int it = 0; it < 8; ++it) {
    const ushort* Xp = (it < 2) ? X0 : (it < 4) ? X1 : (it < 6) ? X2 : X3;
    int kb = (it & 1) * 64;  // column offset within Xp
    int k0 = it * 64;        // column offset within Wt rows
    // stage A (128x64 bf16) and B (128x64 bf16), 16B per thread per pass
    #pragma unroll
    for (int p = 0; p < 4; p++) {
      int idx = t + p * 256;          // 0..1023
      int rj = idx >> 3;              // 0..127
      int kc = (idx & 7) << 3;        // 0..56
      int gr = r0 + rj;
      short8 av = (short8){0,0,0,0,0,0,0,0};
      if (gr < N) av = *(const short8*)(Xp + (size_t)gr * H + kb + kc);
      *(short8*)&As[rj][kc] = av;
      *(short8*)&Bs[rj][kc] = *(const short8*)(Wt + (size_t)rj * 512 + k0 + kc);
    }
    __syncthreads();
    #pragma unroll
    for (int ks = 0; ks < 2; ks++) {
      int kk = ks * 32 + l4 * 8;
      short8 a[4], b[4];
      #pragma unroll
      for (int mf = 0; mf < 4; mf++) a[mf] = *(const short8*)&As[mw * 64 + mf * 16 + l15][kk];
      #pragma unroll
      for (int nf = 0; nf < 4; nf++) b[nf] = *(const short8*)&Bs[nw * 64 + nf * 16 + l15][kk];
      #pragma unroll
      for (int mf = 0; mf < 4; mf++)
        #pragma unroll
        for (int nf = 0; nf < 4; nf++)
          acc[mf][nf] = __builtin_amdgcn_mfma_f32_16x16x32_bf16(a[mf], b[nf], acc[mf][nf], 0, 0, 0);
    }
    __syncthreads();
  }

  // epilogue: bias + relu + bf16 store.  row = r0+mw*64+mf*16+l4*4+r, col = nw*64+nf*16+l15
  #pragma unroll
  for (int nf = 0; nf < 4; nf++) {
    int colj = nw * 64 + nf * 16 + l15;
    float bv = bias[colj];
    #pragma unroll
    for (int mf = 0; mf < 4; mf++) {
      int rbase = r0 + mw * 64 + mf * 16 + l4 * 4;
      #pragma unroll
      for (int r = 0; r < 4; r++) {
        int rr = rbase + r;
        if (rr < N) {
          float v = acc[mf][nf][r] + bv;
          v = fmaxf(v, 0.f);
          O[(size_t)rr * H + colj] = f2bf(v);
        }
      }
    }
  }
}

// ---------------- global mean pool: parallel atomic sums ----------------
#define POOL_ROWS 64
__global__ __launch_bounds__(256) void k_pool(const ushort* __restrict__ h,
                                              const int* __restrict__ batch,
                                              float* __restrict__ pooled, int N) {
  int r0 = blockIdx.x * POOL_ROWS;
  int j = threadIdx.x & 127;
  int half = threadIdx.x >> 7;
  int rend = min(r0 + POOL_ROWS, N);
  float acc = 0.f;
  int cur = -1;
  for (int r = r0 + half; r < rend; r += 2) {
    int g = batch[r];
    if (g != cur) {
      if (cur >= 0) atomicAdd(&pooled[cur * H + j], acc);
      cur = g;
      acc = 0.f;
    }
    acc += bf2f(h[(size_t)r * H + j]);
  }
  if (cur >= 0) atomicAdd(&pooled[cur * H + j], acc);
}

// ---------------- head: sigmoid((mean @ W1 + b1) @ W2 + b2), bounds inline ----------------
__global__ __launch_bounds__(128) void k_head(const float* __restrict__ pooled,
                                              const int* __restrict__ batch, int N,
                                              const float* __restrict__ w1,
                                              const float* __restrict__ b1,
                                              const float* __restrict__ w2,
                                              const float* __restrict__ b2,
                                              float* __restrict__ out) {
  int g = blockIdx.x;
  int j = threadIdx.x;
  __shared__ float pv[H];
  __shared__ float red[H];
  __shared__ int bnd[2];
  if (j < 2) {
    int target = g + j;
    int lo = 0, hi = N;
    while (lo < hi) {
      int mid = (lo + hi) >> 1;
      if (batch[mid] < target) lo = mid + 1;
      else hi = mid;
    }
    bnd[j] = lo;
  }
  __syncthreads();
  float c = (float)max(bnd[1] - bnd[0], 1);
  pv[j] = pooled[g * H + j] / c;
  __syncthreads();
  float t1 = b1[j];
  #pragma unroll 4
  for (int k = 0; k < H; k++) t1 = fmaf(pv[k], w1[k * H + j], t1);
  red[j] = t1 * w2[j];
  __syncthreads();
  if (j < 64) {
    float s = red[j] + red[j + 64];
    #pragma unroll
    for (int o = 32; o; o >>= 1) s += __shfl_down(s, o);
    if (j == 0) out[g] = 1.f / (1.f + expf(-(s + b2[0])));
  }
}

extern "C" void kernel_launch(void* const* d_in, const int* in_sizes, int n_in,
                              void* d_out, int out_size, void* d_ws, size_t ws_size,
                              hipStream_t stream) {
  const float* x = (const float*)d_in[0];
  const int* eidx = (const int*)d_in[1];
  const float* ew = (const float*)d_in[2];
  const int* batch = (const int*)d_in[3];
  const float* conv_ws = (const float*)d_in[4];  // [5][4][128][128]
  const float* conv_bs = (const float*)d_in[5];  // [5][128]
  const float* lin1_w = (const float*)d_in[6];
  const float* lin1_b = (const float*)d_in[7];
  const float* lin2_w = (const float*)d_in[8];
  const float* lin2_b = (const float*)d_in[9];
  float* out = (float*)d_out;

  const int N = in_sizes[0] / H;  // 50000
  const int E = in_sizes[2];      // 800000
  const int* row = eidx;
  const int* col = eidx + E;

  char* p = (char*)d_ws;
  auto alloc = [&](size_t bytes) {
    char* q = p;
    p += (bytes + 255) & ~(size_t)255;
    return q;
  };
  float* deg = (float*)alloc((size_t)N * 4);
  int* cnt = (int*)alloc((size_t)N * 4);
  int* ptrb = (int*)alloc((size_t)(N + 1) * 4);
  int* cursor = (int*)alloc((size_t)N * 4);
  int2* es = (int2*)alloc((size_t)E * 8);
  ushort* xb = (ushort*)alloc((size_t)N * H * 2);
  ushort* B0 = (ushort*)alloc((size_t)N * H * 2);
  ushort* B1 = (ushort*)alloc((size_t)N * H * 2);
  ushort* B2 = (ushort*)alloc((size_t)N * H * 2);
  ushort* B3 = (ushort*)alloc((size_t)N * H * 2);
  ushort* Wt = (ushort*)alloc((size_t)5 * H * 512 * 2);
  int* bsum = (int*)alloc(256 * 4);
  int* boff = (int*)alloc(256 * 4);
  float* pooled = (float*)alloc((size_t)NGRAPH * H * 4);

  hipMemsetAsync(deg, 0, (size_t)N * 4, stream);
  hipMemsetAsync(cnt, 0, (size_t)N * 4, stream);
  hipMemsetAsync(pooled, 0, (size_t)NGRAPH * H * 4, stream);

  int eb = (E + 255) / 256;
  int nb = (N + 255) / 256;  // 196 <= 256
  k_cvt_x<<<(N * H / 4 + 255) / 256, 256, 0, stream>>>(x, xb, N * H / 4);
  k_cvt_w<<<(5 * H * 512 + 255) / 256, 256, 0, stream>>>(conv_ws, Wt, 5 * H * 512);
  k_deg_count<<<eb, 256, 0, stream>>>(col, ew, deg, cnt, E);
  k_scan1<<<nb, 256, 0, stream>>>(cnt, bsum, N);
  k_scan2<<<1, 256, 0, stream>>>(bsum, boff, nb);
  k_scan3<<<nb, 256, 0, stream>>>(cnt, boff, ptrb, cursor, N);
  k_norm_scatter<<<eb, 256, 0, stream>>>(row, col, ew, deg, cursor, es, E);

  int gemm_blocks = (N + 127) / 128;
  int prop_blocks = (N + 3) / 4;  // 4 waves (nodes) per 256-thread block

  const ushort* P = xb;
  for (int layer = 0; layer < 5; layer++) {
    const ushort* Wl = Wt + (size_t)layer * H * 512;
    const float* bl = conv_bs + (size_t)layer * H;
    k_prop<<<prop_blocks, 256, 0, stream>>>(P, B0, ptrb, es, N);
    k_prop<<<prop_blocks, 256, 0, stream>>>(B0, B1, ptrb, es, N);
    k_prop<<<prop_blocks, 256, 0, stream>>>(B1, B2, ptrb, es, N);
    // O=B3 aliases P for layers>=1: each block writes only its own rows, after
    // its last read of those rows -> safe.
    k_fgemm<<<gemm_blocks, 256, 0, stream>>>(P, B0, B1, B2, Wl, bl, B3, N);
    P = B3;
  }

  k_pool<<<(N + POOL_ROWS - 1) / POOL_ROWS, 256, 0, stream>>>(P, batch, pooled, N);
  k_head<<<NGRAPH, 128, 0, stream>>>(pooled, batch, N, lin1_w, lin1_b, lin2_w, lin2_b, out);
}

// Round 4
// 764.427 us; speedup vs baseline: 2.6536x; 1.1229x over previous
//
#include <hip/hip_runtime.h>
#include <math.h>

#define H 128
#define NGRAPH 64

using short8 = __attribute__((ext_vector_type(8))) short;
using f32x4 = __attribute__((ext_vector_type(4))) float;

__device__ inline float bf2f(ushort u) {
  unsigned int b = ((unsigned int)u) << 16;
  return __builtin_bit_cast(float, b);
}
__device__ inline ushort f2bf(float f) {
  unsigned int u = __builtin_bit_cast(unsigned int, f);
  u = (u + 0x7FFF + ((u >> 16) & 1)) >> 16;  // RNE
  return (ushort)u;
}

// ---------------- x fp32 -> bf16 ----------------
__global__ __launch_bounds__(256) void k_cvt_x(const float* __restrict__ x,
                                               ushort* __restrict__ xb, int total4) {
  int i = blockIdx.x * blockDim.x + threadIdx.x;
  if (i >= total4) return;
  float4 v = *(const float4*)(x + (size_t)i * 4);
  ushort4 o;
  o.x = f2bf(v.x); o.y = f2bf(v.y); o.z = f2bf(v.z); o.w = f2bf(v.w);
  *(ushort4*)(xb + (size_t)i * 4) = o;
}

// ---------------- transpose+convert weights: Wt[l][j][k] = W[l][k/128][k%128][j] ----------------
__global__ __launch_bounds__(256) void k_cvt_w(const float* __restrict__ w,
                                               ushort* __restrict__ wt, int total) {
  int i = blockIdx.x * blockDim.x + threadIdx.x;
  if (i >= total) return;           // total = 5*128*512
  int l = i >> 16;                  // /65536
  int rem = i & 65535;
  int j = rem >> 9;                 // 0..127
  int k = rem & 511;                // 0..511
  int q = k >> 7, kk = k & 127;
  float v = w[(((size_t)l * 4 + q) * H + kk) * H + j];
  wt[i] = f2bf(v);
}

// ---------------- count: rank[e] = old cnt[col[e]]++ (the ONLY atomic pass) ----------------
__global__ void k_count(const int* __restrict__ col, int* __restrict__ cnt,
                        int* __restrict__ rank, int E) {
  int e = blockIdx.x * blockDim.x + threadIdx.x;
  if (e < E) rank[e] = atomicAdd(&cnt[col[e]], 1);
}

// ---------------- parallel 3-phase exclusive scan ----------------
__global__ __launch_bounds__(256) void k_scan1(const int* __restrict__ cnt,
                                               int* __restrict__ bsum, int N) {
  int i = blockIdx.x * 256 + threadIdx.x;
  int v = (i < N) ? cnt[i] : 0;
  __shared__ int red[256];
  red[threadIdx.x] = v;
  __syncthreads();
  #pragma unroll
  for (int o = 128; o; o >>= 1) {
    if (threadIdx.x < o) red[threadIdx.x] += red[threadIdx.x + o];
    __syncthreads();
  }
  if (threadIdx.x == 0) bsum[blockIdx.x] = red[0];
}

__global__ __launch_bounds__(256) void k_scan2(const int* __restrict__ bsum,
                                               int* __restrict__ boff, int nb) {
  __shared__ int s[256];
  int t = threadIdx.x;
  int v = (t < nb) ? bsum[t] : 0;
  s[t] = v;
  __syncthreads();
  #pragma unroll
  for (int d = 1; d < 256; d <<= 1) {
    int u = (t >= d) ? s[t - d] : 0;
    __syncthreads();
    s[t] += u;
    __syncthreads();
  }
  if (t < nb) boff[t] = s[t] - v;  // exclusive prefix
}

__global__ __launch_bounds__(256) void k_scan3(const int* __restrict__ cnt,
                                               const int* __restrict__ boff,
                                               int* __restrict__ ptr, int N) {
  int t = threadIdx.x;
  int i = blockIdx.x * 256 + t;
  int v = (i < N) ? cnt[i] : 0;
  __shared__ int s[256];
  s[t] = v;
  __syncthreads();
  #pragma unroll
  for (int d = 1; d < 256; d <<= 1) {
    int u = (t >= d) ? s[t - d] : 0;
    __syncthreads();
    s[t] += u;
    __syncthreads();
  }
  int ex = boff[blockIdx.x] + s[t] - v;
  if (i < N) {
    ptr[i] = ex;
    if (i == N - 1) ptr[N] = ex + v;
  }
}

// ---------------- scatter (row, w) into CSC order — NO atomics ----------------
__global__ void k_scatter(const int* __restrict__ row, const int* __restrict__ col,
                          const float* __restrict__ w, const int* __restrict__ ptr,
                          const int* __restrict__ rank, int2* __restrict__ es, int E) {
  int e = blockIdx.x * blockDim.x + threadIdx.x;
  if (e < E) {
    int pos = ptr[col[e]] + rank[e];
    int2 pk;
    pk.x = row[e];
    pk.y = __builtin_bit_cast(int, w[e]);
    es[pos] = pk;
  }
}

// ---------------- per-node degree -> dis = rsqrt(deg) ----------------
__global__ __launch_bounds__(256) void k_degnorm1(const int* __restrict__ ptr,
                                                  const int2* __restrict__ es,
                                                  float* __restrict__ dis, int N) {
  int v = blockIdx.x * blockDim.x + threadIdx.x;
  if (v >= N) return;
  int s = ptr[v], e = ptr[v + 1];
  float d = 0.f;
  for (int i = s; i < e; i++) d += __builtin_bit_cast(float, es[i].y);
  dis[v] = d > 0.f ? rsqrtf(d) : 0.f;
}

// ---------------- per-edge norm: es.y = dis[row]*w*dis[col] (in CSC order) ----------------
__global__ __launch_bounds__(256) void k_degnorm2(const int* __restrict__ ptr,
                                                  int2* __restrict__ es,
                                                  const float* __restrict__ dis, int N) {
  int v = blockIdx.x * blockDim.x + threadIdx.x;
  if (v >= N) return;
  int s = ptr[v], e = ptr[v + 1];
  float dv = dis[v];
  for (int i = s; i < e; i++) {
    int2 ed = es[i];
    float nm = dis[ed.x] * __builtin_bit_cast(float, ed.y) * dv;
    es[i].y = __builtin_bit_cast(int, nm);
  }
}

// ---------------- propagation (bf16 in/out): hout[v] = sum_e norm_e * hin[row_e] ----------------
// one wave per dst node; 4 groups of 16 lanes process 4 edges concurrently;
// each lane loads 16B (8 bf16 channels); cross-group shuffle reduce at end.
__global__ __launch_bounds__(256) void k_prop(const ushort* __restrict__ hin,
                                              ushort* __restrict__ hout,
                                              const int* __restrict__ ptr,
                                              const int2* __restrict__ es, int N) {
  int wid = (int)((blockIdx.x * (unsigned)blockDim.x + threadIdx.x) >> 6);
  wid = __builtin_amdgcn_readfirstlane(wid);
  if (wid >= N) return;
  int lane = threadIdx.x & 63;
  int grp = lane >> 4;   // 0..3: which edge within a 4-edge batch
  int l15 = lane & 15;   // channel block: 8 bf16 at l15*8
  int s = ptr[wid], e = ptr[wid + 1];
  float acc[8] = {0.f, 0.f, 0.f, 0.f, 0.f, 0.f, 0.f, 0.f};
  const ushort* base = hin + l15 * 8;
  for (int i = s + grp; i < e; i += 4) {
    int2 ed = es[i];
    float nm = __builtin_bit_cast(float, ed.y);
    short8 v = *(const short8*)(base + (size_t)ed.x * H);
    #pragma unroll
    for (int j = 0; j < 8; j++) acc[j] = fmaf(nm, bf2f((ushort)v[j]), acc[j]);
  }
  // reduce across the 4 groups (lanes differing in bits 4,5)
  #pragma unroll
  for (int j = 0; j < 8; j++) {
    acc[j] += __shfl_xor(acc[j], 16);
    acc[j] += __shfl_xor(acc[j], 32);
  }
  // each lane stores one dword: channels l15*8 + grp*2, +1
  unsigned int o = (unsigned int)f2bf(acc[grp * 2]) | ((unsigned int)f2bf(acc[grp * 2 + 1]) << 16);
  *(unsigned int*)(hout + (size_t)wid * H + l15 * 8 + grp * 2) = o;
}

// ---------------- fused TAGConv GEMM: O = relu([X0|X1|X2|X3] @ Wcat + b) ----------------
__global__ __launch_bounds__(256) void k_fgemm(const ushort* __restrict__ X0,
                                               const ushort* __restrict__ X1,
                                               const ushort* __restrict__ X2,
                                               const ushort* __restrict__ X3,
                                               const ushort* __restrict__ Wt,  // [128][512] bf16 (j-major)
                                               const float* __restrict__ bias,
                                               ushort* __restrict__ O, int N) {
  __shared__ ushort As[128][72];
  __shared__ ushort Bs[128][72];
  int t = threadIdx.x;
  int r0 = blockIdx.x * 128;
  int w = t >> 6, lane = t & 63;
  int mw = w >> 1, nw = w & 1;
  int l15 = lane & 15, l4 = lane >> 4;

  f32x4 acc[4][4];
  #pragma unroll
  for (int i = 0; i < 4; i++)
    #pragma unroll
    for (int j = 0; j < 4; j++) acc[i][j] = (f32x4){0.f, 0.f, 0.f, 0.f};

  for (int it = 0; it < 8; ++it) {
    const ushort* Xp = (it < 2) ? X0 : (it < 4) ? X1 : (it < 6) ? X2 : X3;
    int kb = (it & 1) * 64;
    int k0 = it * 64;
    #pragma unroll
    for (int p = 0; p < 4; p++) {
      int idx = t + p * 256;
      int rj = idx >> 3;
      int kc = (idx & 7) << 3;
      int gr = r0 + rj;
      short8 av = (short8){0, 0, 0, 0, 0, 0, 0, 0};
      if (gr < N) av = *(const short8*)(Xp + (size_t)gr * H + kb + kc);
      *(short8*)&As[rj][kc] = av;
      *(short8*)&Bs[rj][kc] = *(const short8*)(Wt + (size_t)rj * 512 + k0 + kc);
    }
    __syncthreads();
    #pragma unroll
    for (int ks = 0; ks < 2; ks++) {
      int kk = ks * 32 + l4 * 8;
      short8 a[4], b[4];
      #pragma unroll
      for (int mf = 0; mf < 4; mf++) a[mf] = *(const short8*)&As[mw * 64 + mf * 16 + l15][kk];
      #pragma unroll
      for (int nf = 0; nf < 4; nf++) b[nf] = *(const short8*)&Bs[nw * 64 + nf * 16 + l15][kk];
      #pragma unroll
      for (int mf = 0; mf < 4; mf++)
        #pragma unroll
        for (int nf = 0; nf < 4; nf++)
          acc[mf][nf] = __builtin_amdgcn_mfma_f32_16x16x32_bf16(a[mf], b[nf], acc[mf][nf], 0, 0, 0);
    }
    __syncthreads();
  }

  #pragma unroll
  for (int nf = 0; nf < 4; nf++) {
    int colj = nw * 64 + nf * 16 + l15;
    float bv = bias[colj];
    #pragma unroll
    for (int mf = 0; mf < 4; mf++) {
      int rbase = r0 + mw * 64 + mf * 16 + l4 * 4;
      #pragma unroll
      for (int r = 0; r < 4; r++) {
        int rr = rbase + r;
        if (rr < N) {
          float v = acc[mf][nf][r] + bv;
          v = fmaxf(v, 0.f);
          O[(size_t)rr * H + colj] = f2bf(v);
        }
      }
    }
  }
}

// ---------------- global mean pool: parallel atomic sums ----------------
#define POOL_ROWS 64
__global__ __launch_bounds__(256) void k_pool(const ushort* __restrict__ h,
                                              const int* __restrict__ batch,
                                              float* __restrict__ pooled, int N) {
  int r0 = blockIdx.x * POOL_ROWS;
  int j = threadIdx.x & 127;
  int half = threadIdx.x >> 7;
  int rend = min(r0 + POOL_ROWS, N);
  float acc = 0.f;
  int cur = -1;
  for (int r = r0 + half; r < rend; r += 2) {
    int g = batch[r];
    if (g != cur) {
      if (cur >= 0) atomicAdd(&pooled[cur * H + j], acc);
      cur = g;
      acc = 0.f;
    }
    acc += bf2f(h[(size_t)r * H + j]);
  }
  if (cur >= 0) atomicAdd(&pooled[cur * H + j], acc);
}

// ---------------- head: sigmoid((mean @ W1 + b1) @ W2 + b2), bounds inline ----------------
__global__ __launch_bounds__(128) void k_head(const float* __restrict__ pooled,
                                              const int* __restrict__ batch, int N,
                                              const float* __restrict__ w1,
                                              const float* __restrict__ b1,
                                              const float* __restrict__ w2,
                                              const float* __restrict__ b2,
                                              float* __restrict__ out) {
  int g = blockIdx.x;
  int j = threadIdx.x;
  __shared__ float pv[H];
  __shared__ float red[H];
  __shared__ int bnd[2];
  if (j < 2) {
    int target = g + j;
    int lo = 0, hi = N;
    while (lo < hi) {
      int mid = (lo + hi) >> 1;
      if (batch[mid] < target) lo = mid + 1;
      else hi = mid;
    }
    bnd[j] = lo;
  }
  __syncthreads();
  float c = (float)max(bnd[1] - bnd[0], 1);
  pv[j] = pooled[g * H + j] / c;
  __syncthreads();
  float t1 = b1[j];
  #pragma unroll 4
  for (int k = 0; k < H; k++) t1 = fmaf(pv[k], w1[k * H + j], t1);
  red[j] = t1 * w2[j];
  __syncthreads();
  if (j < 64) {
    float s = red[j] + red[j + 64];
    #pragma unroll
    for (int o = 32; o; o >>= 1) s += __shfl_down(s, o);
    if (j == 0) out[g] = 1.f / (1.f + expf(-(s + b2[0])));
  }
}

extern "C" void kernel_launch(void* const* d_in, const int* in_sizes, int n_in,
                              void* d_out, int out_size, void* d_ws, size_t ws_size,
                              hipStream_t stream) {
  const float* x = (const float*)d_in[0];
  const int* eidx = (const int*)d_in[1];
  const float* ew = (const float*)d_in[2];
  const int* batch = (const int*)d_in[3];
  const float* conv_ws = (const float*)d_in[4];  // [5][4][128][128]
  const float* conv_bs = (const float*)d_in[5];  // [5][128]
  const float* lin1_w = (const float*)d_in[6];
  const float* lin1_b = (const float*)d_in[7];
  const float* lin2_w = (const float*)d_in[8];
  const float* lin2_b = (const float*)d_in[9];
  float* out = (float*)d_out;

  const int N = in_sizes[0] / H;  // 50000
  const int E = in_sizes[2];      // 800000
  const int* row = eidx;
  const int* col = eidx + E;

  char* p = (char*)d_ws;
  auto alloc = [&](size_t bytes) {
    char* q = p;
    p += (bytes + 255) & ~(size_t)255;
    return q;
  };
  int* cnt = (int*)alloc((size_t)N * 4);
  int* ptrb = (int*)alloc((size_t)(N + 1) * 4);
  int* rank = (int*)alloc((size_t)E * 4);
  float* dis = (float*)alloc((size_t)N * 4);
  int2* es = (int2*)alloc((size_t)E * 8);
  ushort* xb = (ushort*)alloc((size_t)N * H * 2);
  ushort* B0 = (ushort*)alloc((size_t)N * H * 2);
  ushort* B1 = (ushort*)alloc((size_t)N * H * 2);
  ushort* B2 = (ushort*)alloc((size_t)N * H * 2);
  ushort* B3 = (ushort*)alloc((size_t)N * H * 2);
  ushort* Wt = (ushort*)alloc((size_t)5 * H * 512 * 2);
  int* bsum = (int*)alloc(256 * 4);
  int* boff = (int*)alloc(256 * 4);
  float* pooled = (float*)alloc((size_t)NGRAPH * H * 4);

  hipMemsetAsync(cnt, 0, (size_t)N * 4, stream);
  hipMemsetAsync(pooled, 0, (size_t)NGRAPH * H * 4, stream);

  int eb = (E + 255) / 256;
  int nb = (N + 255) / 256;   // 196 <= 256
  int nt = (N + 255) / 256;
  k_cvt_x<<<(N * H / 4 + 255) / 256, 256, 0, stream>>>(x, xb, N * H / 4);
  k_cvt_w<<<(5 * H * 512 + 255) / 256, 256, 0, stream>>>(conv_ws, Wt, 5 * H * 512);
  k_count<<<eb, 256, 0, stream>>>(col, cnt, rank, E);
  k_scan1<<<nb, 256, 0, stream>>>(cnt, bsum, N);
  k_scan2<<<1, 256, 0, stream>>>(bsum, boff, nb);
  k_scan3<<<nb, 256, 0, stream>>>(cnt, boff, ptrb, N);
  k_scatter<<<eb, 256, 0, stream>>>(row, col, ew, ptrb, rank, es, E);
  k_degnorm1<<<nt, 256, 0, stream>>>(ptrb, es, dis, N);
  k_degnorm2<<<nt, 256, 0, stream>>>(ptrb, es, dis, N);

  int gemm_blocks = (N + 127) / 128;
  int prop_blocks = (N + 3) / 4;  // 4 waves (nodes) per 256-thread block

  const ushort* P = xb;
  for (int layer = 0; layer < 5; layer++) {
    const ushort* Wl = Wt + (size_t)layer * H * 512;
    const float* bl = conv_bs + (size_t)layer * H;
    k_prop<<<prop_blocks, 256, 0, stream>>>(P, B0, ptrb, es, N);
    k_prop<<<prop_blocks, 256, 0, stream>>>(B0, B1, ptrb, es, N);
    k_prop<<<prop_blocks, 256, 0, stream>>>(B1, B2, ptrb, es, N);
    // O=B3 aliases P for layers>=1: each block writes only its own rows, after
    // its last read of those rows -> safe.
    k_fgemm<<<gemm_blocks, 256, 0, stream>>>(P, B0, B1, B2, Wl, bl, B3, N);
    P = B3;
  }

  k_pool<<<(N + POOL_ROWS - 1) / POOL_ROWS, 256, 0, stream>>>(P, batch, pooled, N);
  k_head<<<NGRAPH, 128, 0, stream>>>(pooled, batch, N, lin1_w, lin1_b, lin2_w, lin2_b, out);
}

// Round 5
// 650.581 us; speedup vs baseline: 3.1179x; 1.1750x over previous
//
#include <hip/hip_runtime.h>
#include <math.h>

#define H 128
#define NGRAPH 64

using short8 = __attribute__((ext_vector_type(8))) short;
using f32x4 = __attribute__((ext_vector_type(4))) float;
using f32x2 = __attribute__((ext_vector_type(2))) float;

__device__ inline float bf2f(ushort u) {
  unsigned int b = ((unsigned int)u) << 16;
  return __builtin_bit_cast(float, b);
}
__device__ inline ushort f2bf(float f) {
  unsigned int u = __builtin_bit_cast(unsigned int, f);
  u = (u + 0x7FFF + ((u >> 16) & 1)) >> 16;  // RNE
  return (ushort)u;
}
// pack two f32 -> two fp8(e4m3, OCP) bytes in low 16 bits
__device__ inline unsigned int f32x2_to_fp8(float a, float b) {
  return (unsigned int)__builtin_amdgcn_cvt_pk_fp8_f32(a, b, 0, false) & 0xFFFFu;
}

// ---------------- x fp32 -> bf16 + fp8 ----------------
__global__ __launch_bounds__(256) void k_cvt_x(const float* __restrict__ x,
                                               ushort* __restrict__ xb,
                                               unsigned char* __restrict__ x8, int total4) {
  int i = blockIdx.x * blockDim.x + threadIdx.x;
  if (i >= total4) return;
  float4 v = *(const float4*)(x + (size_t)i * 4);
  ushort4 o;
  o.x = f2bf(v.x); o.y = f2bf(v.y); o.z = f2bf(v.z); o.w = f2bf(v.w);
  *(ushort4*)(xb + (size_t)i * 4) = o;
  int p = __builtin_amdgcn_cvt_pk_fp8_f32(v.x, v.y, 0, false);
  p = __builtin_amdgcn_cvt_pk_fp8_f32(v.z, v.w, p, true);
  *(unsigned int*)(x8 + (size_t)i * 4) = (unsigned int)p;
}

// ---------------- transpose+convert weights: Wt[l][j][k] = W[l][k/128][k%128][j] ----------------
__global__ __launch_bounds__(256) void k_cvt_w(const float* __restrict__ w,
                                               ushort* __restrict__ wt, int total) {
  int i = blockIdx.x * blockDim.x + threadIdx.x;
  if (i >= total) return;           // total = 5*128*512
  int l = i >> 16;                  // /65536
  int rem = i & 65535;
  int j = rem >> 9;                 // 0..127
  int k = rem & 511;                // 0..511
  int q = k >> 7, kk = k & 127;
  float v = w[(((size_t)l * 4 + q) * H + kk) * H + j];
  wt[i] = f2bf(v);
}

// ---------------- count: rank[e] = old cnt[col[e]]++ (the ONLY atomic pass) ----------------
__global__ void k_count(const int* __restrict__ col, int* __restrict__ cnt,
                        int* __restrict__ rank, int E) {
  int e = blockIdx.x * blockDim.x + threadIdx.x;
  if (e < E) rank[e] = atomicAdd(&cnt[col[e]], 1);
}

// ---------------- parallel 3-phase exclusive scan ----------------
__global__ __launch_bounds__(256) void k_scan1(const int* __restrict__ cnt,
                                               int* __restrict__ bsum, int N) {
  int i = blockIdx.x * 256 + threadIdx.x;
  int v = (i < N) ? cnt[i] : 0;
  __shared__ int red[256];
  red[threadIdx.x] = v;
  __syncthreads();
  #pragma unroll
  for (int o = 128; o; o >>= 1) {
    if (threadIdx.x < o) red[threadIdx.x] += red[threadIdx.x + o];
    __syncthreads();
  }
  if (threadIdx.x == 0) bsum[blockIdx.x] = red[0];
}

__global__ __launch_bounds__(256) void k_scan2(const int* __restrict__ bsum,
                                               int* __restrict__ boff, int nb) {
  __shared__ int s[256];
  int t = threadIdx.x;
  int v = (t < nb) ? bsum[t] : 0;
  s[t] = v;
  __syncthreads();
  #pragma unroll
  for (int d = 1; d < 256; d <<= 1) {
    int u = (t >= d) ? s[t - d] : 0;
    __syncthreads();
    s[t] += u;
    __syncthreads();
  }
  if (t < nb) boff[t] = s[t] - v;  // exclusive prefix
}

__global__ __launch_bounds__(256) void k_scan3(const int* __restrict__ cnt,
                                               const int* __restrict__ boff,
                                               int* __restrict__ ptr, int N) {
  int t = threadIdx.x;
  int i = blockIdx.x * 256 + t;
  int v = (i < N) ? cnt[i] : 0;
  __shared__ int s[256];
  s[t] = v;
  __syncthreads();
  #pragma unroll
  for (int d = 1; d < 256; d <<= 1) {
    int u = (t >= d) ? s[t - d] : 0;
    __syncthreads();
    s[t] += u;
    __syncthreads();
  }
  int ex = boff[blockIdx.x] + s[t] - v;
  if (i < N) {
    ptr[i] = ex;
    if (i == N - 1) ptr[N] = ex + v;
  }
}

// ---------------- scatter (row, w) into CSC order — NO atomics ----------------
__global__ void k_scatter(const int* __restrict__ row, const int* __restrict__ col,
                          const float* __restrict__ w, const int* __restrict__ ptr,
                          const int* __restrict__ rank, int2* __restrict__ es, int E) {
  int e = blockIdx.x * blockDim.x + threadIdx.x;
  if (e < E) {
    int pos = ptr[col[e]] + rank[e];
    int2 pk;
    pk.x = row[e];
    pk.y = __builtin_bit_cast(int, w[e]);
    es[pos] = pk;
  }
}

// ---------------- per-node degree -> dis = rsqrt(deg) ----------------
__global__ __launch_bounds__(256) void k_degnorm1(const int* __restrict__ ptr,
                                                  const int2* __restrict__ es,
                                                  float* __restrict__ dis, int N) {
  int v = blockIdx.x * blockDim.x + threadIdx.x;
  if (v >= N) return;
  int s = ptr[v], e = ptr[v + 1];
  float d = 0.f;
  for (int i = s; i < e; i++) d += __builtin_bit_cast(float, es[i].y);
  dis[v] = d > 0.f ? rsqrtf(d) : 0.f;
}

// ---------------- per-edge norm: es.y = dis[row]*w*dis[col] (in CSC order) ----------------
__global__ __launch_bounds__(256) void k_degnorm2(const int* __restrict__ ptr,
                                                  int2* __restrict__ es,
                                                  const float* __restrict__ dis, int N) {
  int v = blockIdx.x * blockDim.x + threadIdx.x;
  if (v >= N) return;
  int s = ptr[v], e = ptr[v + 1];
  float dv = dis[v];
  for (int i = s; i < e; i++) {
    int2 ed = es[i];
    float nm = dis[ed.x] * __builtin_bit_cast(float, ed.y) * dv;
    es[i].y = __builtin_bit_cast(int, nm);
  }
}

// ---------------- propagation: fp8 gather, fp32 accumulate, bf16+fp8 dual write ----
// one wave per dst node; 4 groups of 16 lanes, 8 edges in flight (2x unroll);
// each lane loads 8B (8 fp8 channels); cross-group shuffle reduce at end.
__global__ __launch_bounds__(256) void k_prop(const unsigned char* __restrict__ hin8,
                                              ushort* __restrict__ hout,
                                              unsigned char* __restrict__ hout8,
                                              const int* __restrict__ ptr,
                                              const int2* __restrict__ es, int N) {
  int wid = (int)((blockIdx.x * (unsigned)blockDim.x + threadIdx.x) >> 6);
  wid = __builtin_amdgcn_readfirstlane(wid);
  if (wid >= N) return;
  int lane = threadIdx.x & 63;
  int grp = lane >> 4;   // 0..3: which edge within a 4-edge batch
  int l15 = lane & 15;   // channel block: 8 fp8 at byte l15*8
  int s = ptr[wid], e = ptr[wid + 1];
  float acc[8] = {0.f, 0.f, 0.f, 0.f, 0.f, 0.f, 0.f, 0.f};
  const unsigned char* base = hin8 + l15 * 8;
  int i = s + grp;
  for (; i + 4 < e; i += 8) {
    int2 e0 = es[i];
    int2 e1 = es[i + 4];
    uint2 v0 = *(const uint2*)(base + (size_t)e0.x * H);
    uint2 v1 = *(const uint2*)(base + (size_t)e1.x * H);
    float n0 = __builtin_bit_cast(float, e0.y);
    float n1 = __builtin_bit_cast(float, e1.y);
    f32x2 c;
    c = __builtin_amdgcn_cvt_pk_f32_fp8(v0.x, false); acc[0] = fmaf(n0, c[0], acc[0]); acc[1] = fmaf(n0, c[1], acc[1]);
    c = __builtin_amdgcn_cvt_pk_f32_fp8(v0.x, true);  acc[2] = fmaf(n0, c[0], acc[2]); acc[3] = fmaf(n0, c[1], acc[3]);
    c = __builtin_amdgcn_cvt_pk_f32_fp8(v0.y, false); acc[4] = fmaf(n0, c[0], acc[4]); acc[5] = fmaf(n0, c[1], acc[5]);
    c = __builtin_amdgcn_cvt_pk_f32_fp8(v0.y, true);  acc[6] = fmaf(n0, c[0], acc[6]); acc[7] = fmaf(n0, c[1], acc[7]);
    c = __builtin_amdgcn_cvt_pk_f32_fp8(v1.x, false); acc[0] = fmaf(n1, c[0], acc[0]); acc[1] = fmaf(n1, c[1], acc[1]);
    c = __builtin_amdgcn_cvt_pk_f32_fp8(v1.x, true);  acc[2] = fmaf(n1, c[0], acc[2]); acc[3] = fmaf(n1, c[1], acc[3]);
    c = __builtin_amdgcn_cvt_pk_f32_fp8(v1.y, false); acc[4] = fmaf(n1, c[0], acc[4]); acc[5] = fmaf(n1, c[1], acc[5]);
    c = __builtin_amdgcn_cvt_pk_f32_fp8(v1.y, true);  acc[6] = fmaf(n1, c[0], acc[6]); acc[7] = fmaf(n1, c[1], acc[7]);
  }
  if (i < e) {
    int2 e0 = es[i];
    uint2 v0 = *(const uint2*)(base + (size_t)e0.x * H);
    float n0 = __builtin_bit_cast(float, e0.y);
    f32x2 c;
    c = __builtin_amdgcn_cvt_pk_f32_fp8(v0.x, false); acc[0] = fmaf(n0, c[0], acc[0]); acc[1] = fmaf(n0, c[1], acc[1]);
    c = __builtin_amdgcn_cvt_pk_f32_fp8(v0.x, true);  acc[2] = fmaf(n0, c[0], acc[2]); acc[3] = fmaf(n0, c[1], acc[3]);
    c = __builtin_amdgcn_cvt_pk_f32_fp8(v0.y, false); acc[4] = fmaf(n0, c[0], acc[4]); acc[5] = fmaf(n0, c[1], acc[5]);
    c = __builtin_amdgcn_cvt_pk_f32_fp8(v0.y, true);  acc[6] = fmaf(n0, c[0], acc[6]); acc[7] = fmaf(n0, c[1], acc[7]);
  }
  // reduce across the 4 groups (lanes differing in bits 4,5)
  #pragma unroll
  for (int j = 0; j < 8; j++) {
    acc[j] += __shfl_xor(acc[j], 16);
    acc[j] += __shfl_xor(acc[j], 32);
  }
  // each lane stores channels l15*8 + grp*2, +1 : bf16 dword + fp8 ushort
  float a0 = acc[grp * 2], a1 = acc[grp * 2 + 1];
  unsigned int o = (unsigned int)f2bf(a0) | ((unsigned int)f2bf(a1) << 16);
  *(unsigned int*)(hout + (size_t)wid * H + l15 * 8 + grp * 2) = o;
  *(ushort*)(hout8 + (size_t)wid * H + l15 * 8 + grp * 2) = (ushort)f32x2_to_fp8(a0, a1);
}

// ---------------- fused TAGConv GEMM: O = relu([X0|X1|X2|X3] @ Wcat + b) ----------------
// bf16 inputs, fp32 MFMA accumulate, bf16 + fp8 outputs.
__global__ __launch_bounds__(256) void k_fgemm(const ushort* __restrict__ X0,
                                               const ushort* __restrict__ X1,
                                               const ushort* __restrict__ X2,
                                               const ushort* __restrict__ X3,
                                               const ushort* __restrict__ Wt,  // [128][512] bf16 (j-major)
                                               const float* __restrict__ bias,
                                               ushort* __restrict__ O,
                                               unsigned char* __restrict__ O8, int N) {
  __shared__ ushort As[128][72];
  __shared__ ushort Bs[128][72];
  int t = threadIdx.x;
  int r0 = blockIdx.x * 128;
  int w = t >> 6, lane = t & 63;
  int mw = w >> 1, nw = w & 1;
  int l15 = lane & 15, l4 = lane >> 4;

  f32x4 acc[4][4];
  #pragma unroll
  for (int i = 0; i < 4; i++)
    #pragma unroll
    for (int j = 0; j < 4; j++) acc[i][j] = (f32x4){0.f, 0.f, 0.f, 0.f};

  for (int it = 0; it < 8; ++it) {
    const ushort* Xp = (it < 2) ? X0 : (it < 4) ? X1 : (it < 6) ? X2 : X3;
    int kb = (it & 1) * 64;
    int k0 = it * 64;
    #pragma unroll
    for (int p = 0; p < 4; p++) {
      int idx = t + p * 256;
      int rj = idx >> 3;
      int kc = (idx & 7) << 3;
      int gr = r0 + rj;
      short8 av = (short8){0, 0, 0, 0, 0, 0, 0, 0};
      if (gr < N) av = *(const short8*)(Xp + (size_t)gr * H + kb + kc);
      *(short8*)&As[rj][kc] = av;
      *(short8*)&Bs[rj][kc] = *(const short8*)(Wt + (size_t)rj * 512 + k0 + kc);
    }
    __syncthreads();
    #pragma unroll
    for (int ks = 0; ks < 2; ks++) {
      int kk = ks * 32 + l4 * 8;
      short8 a[4], b[4];
      #pragma unroll
      for (int mf = 0; mf < 4; mf++) a[mf] = *(const short8*)&As[mw * 64 + mf * 16 + l15][kk];
      #pragma unroll
      for (int nf = 0; nf < 4; nf++) b[nf] = *(const short8*)&Bs[nw * 64 + nf * 16 + l15][kk];
      #pragma unroll
      for (int mf = 0; mf < 4; mf++)
        #pragma unroll
        for (int nf = 0; nf < 4; nf++)
          acc[mf][nf] = __builtin_amdgcn_mfma_f32_16x16x32_bf16(a[mf], b[nf], acc[mf][nf], 0, 0, 0);
    }
    __syncthreads();
  }

  #pragma unroll
  for (int nf = 0; nf < 4; nf++) {
    int colj = nw * 64 + nf * 16 + l15;
    float bv = bias[colj];
    #pragma unroll
    for (int mf = 0; mf < 4; mf++) {
      int rbase = r0 + mw * 64 + mf * 16 + l4 * 4;
      #pragma unroll
      for (int r = 0; r < 4; r++) {
        int rr = rbase + r;
        if (rr < N) {
          float v = acc[mf][nf][r] + bv;
          v = fmaxf(v, 0.f);
          O[(size_t)rr * H + colj] = f2bf(v);
          O8[(size_t)rr * H + colj] = (unsigned char)(f32x2_to_fp8(v, v) & 0xFF);
        }
      }
    }
  }
}

// ---------------- global mean pool: parallel atomic sums ----------------
#define POOL_ROWS 64
__global__ __launch_bounds__(256) void k_pool(const ushort* __restrict__ h,
                                              const int* __restrict__ batch,
                                              float* __restrict__ pooled, int N) {
  int r0 = blockIdx.x * POOL_ROWS;
  int j = threadIdx.x & 127;
  int half = threadIdx.x >> 7;
  int rend = min(r0 + POOL_ROWS, N);
  float acc = 0.f;
  int cur = -1;
  for (int r = r0 + half; r < rend; r += 2) {
    int g = batch[r];
    if (g != cur) {
      if (cur >= 0) atomicAdd(&pooled[cur * H + j], acc);
      cur = g;
      acc = 0.f;
    }
    acc += bf2f(h[(size_t)r * H + j]);
  }
  if (cur >= 0) atomicAdd(&pooled[cur * H + j], acc);
}

// ---------------- head: sigmoid((mean @ W1 + b1) @ W2 + b2), bounds inline ----------------
__global__ __launch_bounds__(128) void k_head(const float* __restrict__ pooled,
                                              const int* __restrict__ batch, int N,
                                              const float* __restrict__ w1,
                                              const float* __restrict__ b1,
                                              const float* __restrict__ w2,
                                              const float* __restrict__ b2,
                                              float* __restrict__ out) {
  int g = blockIdx.x;
  int j = threadIdx.x;
  __shared__ float pv[H];
  __shared__ float red[H];
  __shared__ int bnd[2];
  if (j < 2) {
    int target = g + j;
    int lo = 0, hi = N;
    while (lo < hi) {
      int mid = (lo + hi) >> 1;
      if (batch[mid] < target) lo = mid + 1;
      else hi = mid;
    }
    bnd[j] = lo;
  }
  __syncthreads();
  float c = (float)max(bnd[1] - bnd[0], 1);
  pv[j] = pooled[g * H + j] / c;
  __syncthreads();
  float t1 = b1[j];
  #pragma unroll 4
  for (int k = 0; k < H; k++) t1 = fmaf(pv[k], w1[k * H + j], t1);
  red[j] = t1 * w2[j];
  __syncthreads();
  if (j < 64) {
    float s = red[j] + red[j + 64];
    #pragma unroll
    for (int o = 32; o; o >>= 1) s += __shfl_down(s, o);
    if (j == 0) out[g] = 1.f / (1.f + expf(-(s + b2[0])));
  }
}

extern "C" void kernel_launch(void* const* d_in, const int* in_sizes, int n_in,
                              void* d_out, int out_size, void* d_ws, size_t ws_size,
                              hipStream_t stream) {
  const float* x = (const float*)d_in[0];
  const int* eidx = (const int*)d_in[1];
  const float* ew = (const float*)d_in[2];
  const int* batch = (const int*)d_in[3];
  const float* conv_ws = (const float*)d_in[4];  // [5][4][128][128]
  const float* conv_bs = (const float*)d_in[5];  // [5][128]
  const float* lin1_w = (const float*)d_in[6];
  const float* lin1_b = (const float*)d_in[7];
  const float* lin2_w = (const float*)d_in[8];
  const float* lin2_b = (const float*)d_in[9];
  float* out = (float*)d_out;

  const int N = in_sizes[0] / H;  // 50000
  const int E = in_sizes[2];      // 800000
  const int* row = eidx;
  const int* col = eidx + E;

  char* p = (char*)d_ws;
  auto alloc = [&](size_t bytes) {
    char* q = p;
    p += (bytes + 255) & ~(size_t)255;
    return q;
  };
  int* cnt = (int*)alloc((size_t)N * 4);
  int* ptrb = (int*)alloc((size_t)(N + 1) * 4);
  int* rank = (int*)alloc((size_t)E * 4);
  float* dis = (float*)alloc((size_t)N * 4);
  int2* es = (int2*)alloc((size_t)E * 8);
  ushort* xb = (ushort*)alloc((size_t)N * H * 2);
  ushort* B0 = (ushort*)alloc((size_t)N * H * 2);
  ushort* B1 = (ushort*)alloc((size_t)N * H * 2);
  ushort* B2 = (ushort*)alloc((size_t)N * H * 2);
  ushort* B3 = (ushort*)alloc((size_t)N * H * 2);
  unsigned char* x8 = (unsigned char*)alloc((size_t)N * H);
  unsigned char* C0 = (unsigned char*)alloc((size_t)N * H);
  unsigned char* C1 = (unsigned char*)alloc((size_t)N * H);
  unsigned char* C2 = (unsigned char*)alloc((size_t)N * H);
  unsigned char* C3 = (unsigned char*)alloc((size_t)N * H);
  ushort* Wt = (ushort*)alloc((size_t)5 * H * 512 * 2);
  int* bsum = (int*)alloc(256 * 4);
  int* boff = (int*)alloc(256 * 4);
  float* pooled = (float*)alloc((size_t)NGRAPH * H * 4);

  hipMemsetAsync(cnt, 0, (size_t)N * 4, stream);
  hipMemsetAsync(pooled, 0, (size_t)NGRAPH * H * 4, stream);

  int eb = (E + 255) / 256;
  int nb = (N + 255) / 256;   // 196 <= 256
  k_cvt_x<<<(N * H / 4 + 255) / 256, 256, 0, stream>>>(x, xb, x8, N * H / 4);
  k_cvt_w<<<(5 * H * 512 + 255) / 256, 256, 0, stream>>>(conv_ws, Wt, 5 * H * 512);
  k_count<<<eb, 256, 0, stream>>>(col, cnt, rank, E);
  k_scan1<<<nb, 256, 0, stream>>>(cnt, bsum, N);
  k_scan2<<<1, 256, 0, stream>>>(bsum, boff, nb);
  k_scan3<<<nb, 256, 0, stream>>>(cnt, boff, ptrb, N);
  k_scatter<<<eb, 256, 0, stream>>>(row, col, ew, ptrb, rank, es, E);
  k_degnorm1<<<nb, 256, 0, stream>>>(ptrb, es, dis, N);
  k_degnorm2<<<nb, 256, 0, stream>>>(ptrb, es, dis, N);

  int gemm_blocks = (N + 127) / 128;
  int prop_blocks = (N + 3) / 4;  // 4 waves (nodes) per 256-thread block

  const ushort* P = xb;
  const unsigned char* P8 = x8;
  for (int layer = 0; layer < 5; layer++) {
    const ushort* Wl = Wt + (size_t)layer * H * 512;
    const float* bl = conv_bs + (size_t)layer * H;
    k_prop<<<prop_blocks, 256, 0, stream>>>(P8, B0, C0, ptrb, es, N);
    k_prop<<<prop_blocks, 256, 0, stream>>>(C0, B1, C1, ptrb, es, N);
    k_prop<<<prop_blocks, 256, 0, stream>>>(C1, B2, C2, ptrb, es, N);
    // O=B3/C3 aliases P/P8 for layers>=1: each block writes only its own rows,
    // after its last read of those rows; C3 is not read by fgemm -> safe.
    k_fgemm<<<gemm_blocks, 256, 0, stream>>>(P, B0, B1, B2, Wl, bl, B3, C3, N);
    P = B3;
    P8 = C3;
  }

  k_pool<<<(N + POOL_ROWS - 1) / POOL_ROWS, 256, 0, stream>>>(P, batch, pooled, N);
  k_head<<<NGRAPH, 128, 0, stream>>>(pooled, batch, N, lin1_w, lin1_b, lin2_w, lin2_b, out);
}

// Round 6
// 575.003 us; speedup vs baseline: 3.5278x; 1.1314x over previous
//
#include <hip/hip_runtime.h>
#include <math.h>

#define H 128
#define NGRAPH 64

using f32x4 = __attribute__((ext_vector_type(4))) float;
using f32x2 = __attribute__((ext_vector_type(2))) float;

__device__ inline unsigned int f32x2_to_fp8(float a, float b) {
  return (unsigned int)__builtin_amdgcn_cvt_pk_fp8_f32(a, b, 0, false) & 0xFFFFu;
}

// ---------------- x fp32 -> fp8 ----------------
__global__ __launch_bounds__(256) void k_cvt_x(const float* __restrict__ x,
                                               unsigned char* __restrict__ x8, int total4) {
  int i = blockIdx.x * blockDim.x + threadIdx.x;
  if (i >= total4) return;
  float4 v = *(const float4*)(x + (size_t)i * 4);
  int p = __builtin_amdgcn_cvt_pk_fp8_f32(v.x, v.y, 0, false);
  p = __builtin_amdgcn_cvt_pk_fp8_f32(v.z, v.w, p, true);
  *(unsigned int*)(x8 + (size_t)i * 4) = (unsigned int)p;
}

// ---------------- transpose+convert weights to fp8: W8[l][j][k] = W[l][k/128][k%128][j] ----
__global__ __launch_bounds__(256) void k_cvt_w(const float* __restrict__ w,
                                               unsigned char* __restrict__ w8, int total4) {
  int i = blockIdx.x * blockDim.x + threadIdx.x;
  if (i >= total4) return;          // total4 = 5*128*512/4
  int f = i * 4;
  int l = f >> 16;
  int j = (f >> 9) & 127;
  int k = f & 511;                  // k, k+1, k+2, k+3 stay within one q (4 | 128)
  int q = k >> 7, kk = k & 127;
  const float* src = w + (((size_t)(l * 4 + q) * H + kk) * H + j);
  float v0 = src[0], v1 = src[H], v2 = src[2 * H], v3 = src[3 * H];
  int p = __builtin_amdgcn_cvt_pk_fp8_f32(v0, v1, 0, false);
  p = __builtin_amdgcn_cvt_pk_fp8_f32(v2, v3, p, true);
  *(unsigned int*)(w8 + f) = (unsigned int)p;
}

// ---------------- count: rank[e] = old cnt[col[e]]++ (the ONLY atomic pass) ----------------
__global__ void k_count(const int* __restrict__ col, int* __restrict__ cnt,
                        int* __restrict__ rank, int E) {
  int e = blockIdx.x * blockDim.x + threadIdx.x;
  if (e < E) rank[e] = atomicAdd(&cnt[col[e]], 1);
}

// ---------------- parallel 3-phase exclusive scan ----------------
__global__ __launch_bounds__(256) void k_scan1(const int* __restrict__ cnt,
                                               int* __restrict__ bsum, int N) {
  int i = blockIdx.x * 256 + threadIdx.x;
  int v = (i < N) ? cnt[i] : 0;
  __shared__ int red[256];
  red[threadIdx.x] = v;
  __syncthreads();
  #pragma unroll
  for (int o = 128; o; o >>= 1) {
    if (threadIdx.x < o) red[threadIdx.x] += red[threadIdx.x + o];
    __syncthreads();
  }
  if (threadIdx.x == 0) bsum[blockIdx.x] = red[0];
}

__global__ __launch_bounds__(256) void k_scan2(const int* __restrict__ bsum,
                                               int* __restrict__ boff, int nb) {
  __shared__ int s[256];
  int t = threadIdx.x;
  int v = (t < nb) ? bsum[t] : 0;
  s[t] = v;
  __syncthreads();
  #pragma unroll
  for (int d = 1; d < 256; d <<= 1) {
    int u = (t >= d) ? s[t - d] : 0;
    __syncthreads();
    s[t] += u;
    __syncthreads();
  }
  if (t < nb) boff[t] = s[t] - v;  // exclusive prefix
}

__global__ __launch_bounds__(256) void k_scan3(const int* __restrict__ cnt,
                                               const int* __restrict__ boff,
                                               int* __restrict__ ptr, int N) {
  int t = threadIdx.x;
  int i = blockIdx.x * 256 + t;
  int v = (i < N) ? cnt[i] : 0;
  __shared__ int s[256];
  s[t] = v;
  __syncthreads();
  #pragma unroll
  for (int d = 1; d < 256; d <<= 1) {
    int u = (t >= d) ? s[t - d] : 0;
    __syncthreads();
    s[t] += u;
    __syncthreads();
  }
  int ex = boff[blockIdx.x] + s[t] - v;
  if (i < N) {
    ptr[i] = ex;
    if (i == N - 1) ptr[N] = ex + v;
  }
}

// ---------------- scatter (row, w) into CSC order — NO atomics ----------------
__global__ void k_scatter(const int* __restrict__ row, const int* __restrict__ col,
                          const float* __restrict__ w, const int* __restrict__ ptr,
                          const int* __restrict__ rank, int2* __restrict__ es, int E) {
  int e = blockIdx.x * blockDim.x + threadIdx.x;
  if (e < E) {
    int pos = ptr[col[e]] + rank[e];
    int2 pk;
    pk.x = row[e];
    pk.y = __builtin_bit_cast(int, w[e]);
    es[pos] = pk;
  }
}

// ---------------- per-node degree -> dis = rsqrt(deg) ----------------
__global__ __launch_bounds__(256) void k_degnorm1(const int* __restrict__ ptr,
                                                  const int2* __restrict__ es,
                                                  float* __restrict__ dis, int N) {
  int v = blockIdx.x * blockDim.x + threadIdx.x;
  if (v >= N) return;
  int s = ptr[v], e = ptr[v + 1];
  float d = 0.f;
  for (int i = s; i < e; i++) d += __builtin_bit_cast(float, es[i].y);
  dis[v] = d > 0.f ? rsqrtf(d) : 0.f;
}

// ---------------- per-edge norm: es.y = dis[row]*w*dis[col] (in CSC order) ----------------
__global__ __launch_bounds__(256) void k_degnorm2(const int* __restrict__ ptr,
                                                  int2* __restrict__ es,
                                                  const float* __restrict__ dis, int N) {
  int v = blockIdx.x * blockDim.x + threadIdx.x;
  if (v >= N) return;
  int s = ptr[v], e = ptr[v + 1];
  float dv = dis[v];
  for (int i = s; i < e; i++) {
    int2 ed = es[i];
    float nm = dis[ed.x] * __builtin_bit_cast(float, ed.y) * dv;
    es[i].y = __builtin_bit_cast(int, nm);
  }
}

// ---------------- propagation: fp8 gather, fp32 accumulate, fp8 write ----------------
// one wave per dst node; 4 groups of 16 lanes, 8 edges in flight (2x unroll);
// each lane loads 8B (8 fp8 channels); cross-group shuffle reduce at end.
__global__ __launch_bounds__(256) void k_prop(const unsigned char* __restrict__ hin8,
                                              unsigned char* __restrict__ hout8,
                                              const int* __restrict__ ptr,
                                              const int2* __restrict__ es, int N) {
  int wid = (int)((blockIdx.x * (unsigned)blockDim.x + threadIdx.x) >> 6);
  wid = __builtin_amdgcn_readfirstlane(wid);
  if (wid >= N) return;
  int lane = threadIdx.x & 63;
  int grp = lane >> 4;   // 0..3: which edge within a 4-edge batch
  int l15 = lane & 15;   // channel block: 8 fp8 at byte l15*8
  int s = ptr[wid], e = ptr[wid + 1];
  float acc[8] = {0.f, 0.f, 0.f, 0.f, 0.f, 0.f, 0.f, 0.f};
  const unsigned char* base = hin8 + l15 * 8;
  int i = s + grp;
  for (; i + 4 < e; i += 8) {
    int2 e0 = es[i];
    int2 e1 = es[i + 4];
    uint2 v0 = *(const uint2*)(base + (size_t)e0.x * H);
    uint2 v1 = *(const uint2*)(base + (size_t)e1.x * H);
    float n0 = __builtin_bit_cast(float, e0.y);
    float n1 = __builtin_bit_cast(float, e1.y);
    f32x2 c;
    c = __builtin_amdgcn_cvt_pk_f32_fp8(v0.x, false); acc[0] = fmaf(n0, c[0], acc[0]); acc[1] = fmaf(n0, c[1], acc[1]);
    c = __builtin_amdgcn_cvt_pk_f32_fp8(v0.x, true);  acc[2] = fmaf(n0, c[0], acc[2]); acc[3] = fmaf(n0, c[1], acc[3]);
    c = __builtin_amdgcn_cvt_pk_f32_fp8(v0.y, false); acc[4] = fmaf(n0, c[0], acc[4]); acc[5] = fmaf(n0, c[1], acc[5]);
    c = __builtin_amdgcn_cvt_pk_f32_fp8(v0.y, true);  acc[6] = fmaf(n0, c[0], acc[6]); acc[7] = fmaf(n0, c[1], acc[7]);
    c = __builtin_amdgcn_cvt_pk_f32_fp8(v1.x, false); acc[0] = fmaf(n1, c[0], acc[0]); acc[1] = fmaf(n1, c[1], acc[1]);
    c = __builtin_amdgcn_cvt_pk_f32_fp8(v1.x, true);  acc[2] = fmaf(n1, c[0], acc[2]); acc[3] = fmaf(n1, c[1], acc[3]);
    c = __builtin_amdgcn_cvt_pk_f32_fp8(v1.y, false); acc[4] = fmaf(n1, c[0], acc[4]); acc[5] = fmaf(n1, c[1], acc[5]);
    c = __builtin_amdgcn_cvt_pk_f32_fp8(v1.y, true);  acc[6] = fmaf(n1, c[0], acc[6]); acc[7] = fmaf(n1, c[1], acc[7]);
  }
  if (i < e) {
    int2 e0 = es[i];
    uint2 v0 = *(const uint2*)(base + (size_t)e0.x * H);
    float n0 = __builtin_bit_cast(float, e0.y);
    f32x2 c;
    c = __builtin_amdgcn_cvt_pk_f32_fp8(v0.x, false); acc[0] = fmaf(n0, c[0], acc[0]); acc[1] = fmaf(n0, c[1], acc[1]);
    c = __builtin_amdgcn_cvt_pk_f32_fp8(v0.x, true);  acc[2] = fmaf(n0, c[0], acc[2]); acc[3] = fmaf(n0, c[1], acc[3]);
    c = __builtin_amdgcn_cvt_pk_f32_fp8(v0.y, false); acc[4] = fmaf(n0, c[0], acc[4]); acc[5] = fmaf(n0, c[1], acc[5]);
    c = __builtin_amdgcn_cvt_pk_f32_fp8(v0.y, true);  acc[6] = fmaf(n0, c[0], acc[6]); acc[7] = fmaf(n0, c[1], acc[7]);
  }
  // reduce across the 4 groups (lanes differing in bits 4,5)
  #pragma unroll
  for (int j = 0; j < 8; j++) {
    acc[j] += __shfl_xor(acc[j], 16);
    acc[j] += __shfl_xor(acc[j], 32);
  }
  // each lane stores channels l15*8 + grp*2, +1 as 2 fp8 bytes
  *(ushort*)(hout8 + (size_t)wid * H + l15 * 8 + grp * 2) =
      (ushort)f32x2_to_fp8(acc[grp * 2], acc[grp * 2 + 1]);
}

// ---------------- fused TAGConv GEMM (fp8 MFMA): O8 = relu([X0|X1|X2|X3] @ Wcat + b) ----
// fp8 inputs + weights, fp32 MFMA accumulate, fp8 output.
__global__ __launch_bounds__(256) void k_fgemm(const unsigned char* __restrict__ X0,
                                               const unsigned char* __restrict__ X1,
                                               const unsigned char* __restrict__ X2,
                                               const unsigned char* __restrict__ X3,
                                               const unsigned char* __restrict__ W8,  // [128][512] fp8 (j-major)
                                               const float* __restrict__ bias,
                                               unsigned char* __restrict__ O8, int N) {
  __shared__ unsigned char As[128][72];  // [row][k] pad 8 -> 8B-aligned, <=2-way banks
  __shared__ unsigned char Bs[128][72];  // [col j][k]
  int t = threadIdx.x;
  int r0 = blockIdx.x * 128;
  int w = t >> 6, lane = t & 63;
  int mw = w >> 1, nw = w & 1;
  int l15 = lane & 15, l4 = lane >> 4;

  f32x4 acc[4][4];
  #pragma unroll
  for (int i = 0; i < 4; i++)
    #pragma unroll
    for (int j = 0; j < 4; j++) acc[i][j] = (f32x4){0.f, 0.f, 0.f, 0.f};

  for (int it = 0; it < 8; ++it) {
    const unsigned char* Xp = (it < 2) ? X0 : (it < 4) ? X1 : (it < 6) ? X2 : X3;
    int kb = (it & 1) * 64;  // byte (=k) offset within Xp row
    int k0 = it * 64;        // k offset within W8 rows
    // stage A (128x64 fp8) and B (128x64 fp8), 16B per thread per pass, 2 passes
    #pragma unroll
    for (int p = 0; p < 2; p++) {
      int idx = t + p * 256;          // 0..511
      int rj = idx >> 2;              // 0..127
      int kc = (idx & 3) << 4;        // 0,16,32,48
      int gr = r0 + rj;
      uint4 av = make_uint4(0, 0, 0, 0);
      if (gr < N) av = *(const uint4*)(Xp + (size_t)gr * H + kb + kc);
      *(uint4*)&As[rj][kc] = av;
      *(uint4*)&Bs[rj][kc] = *(const uint4*)(W8 + (size_t)rj * 512 + k0 + kc);
    }
    __syncthreads();
    #pragma unroll
    for (int ks = 0; ks < 2; ks++) {
      int kk = ks * 32 + l4 * 8;  // 8 contiguous fp8 K-elems per lane
      long a[4], b[4];
      #pragma unroll
      for (int mf = 0; mf < 4; mf++) a[mf] = *(const long*)&As[mw * 64 + mf * 16 + l15][kk];
      #pragma unroll
      for (int nf = 0; nf < 4; nf++) b[nf] = *(const long*)&Bs[nw * 64 + nf * 16 + l15][kk];
      #pragma unroll
      for (int mf = 0; mf < 4; mf++)
        #pragma unroll
        for (int nf = 0; nf < 4; nf++)
          acc[mf][nf] = __builtin_amdgcn_mfma_f32_16x16x32_fp8_fp8(a[mf], b[nf], acc[mf][nf], 0, 0, 0);
    }
    __syncthreads();
  }

  // epilogue: bias + relu + fp8 store. row = r0+mw*64+mf*16+l4*4+r, col = nw*64+nf*16+l15
  #pragma unroll
  for (int nf = 0; nf < 4; nf++) {
    int colj = nw * 64 + nf * 16 + l15;
    float bv = bias[colj];
    #pragma unroll
    for (int mf = 0; mf < 4; mf++) {
      int rbase = r0 + mw * 64 + mf * 16 + l4 * 4;
      #pragma unroll
      for (int r = 0; r < 4; r++) {
        int rr = rbase + r;
        if (rr < N) {
          float v = fmaxf(acc[mf][nf][r] + bv, 0.f);
          O8[(size_t)rr * H + colj] =
              (unsigned char)(__builtin_amdgcn_cvt_pk_fp8_f32(v, v, 0, false) & 0xFF);
        }
      }
    }
  }
}

// ---------------- global mean pool (fp8 in): parallel atomic sums ----------------
#define POOL_ROWS 64
__global__ __launch_bounds__(256) void k_pool(const unsigned char* __restrict__ h8,
                                              const int* __restrict__ batch,
                                              float* __restrict__ pooled, int N) {
  int r0 = blockIdx.x * POOL_ROWS;
  int j2 = threadIdx.x & 63;   // channel pair: channels 2*j2, 2*j2+1
  int q = threadIdx.x >> 6;    // 0..3: row subset
  int rend = min(r0 + POOL_ROWS, N);
  float a0 = 0.f, a1 = 0.f;
  int cur = -1;
  for (int r = r0 + q; r < rend; r += 4) {
    int g = batch[r];
    if (g != cur) {
      if (cur >= 0) {
        atomicAdd(&pooled[cur * H + 2 * j2], a0);
        atomicAdd(&pooled[cur * H + 2 * j2 + 1], a1);
      }
      cur = g;
      a0 = a1 = 0.f;
    }
    unsigned int v = *(const ushort*)(h8 + (size_t)r * H + 2 * j2);
    f32x2 c = __builtin_amdgcn_cvt_pk_f32_fp8(v, false);
    a0 += c[0];
    a1 += c[1];
  }
  if (cur >= 0) {
    atomicAdd(&pooled[cur * H + 2 * j2], a0);
    atomicAdd(&pooled[cur * H + 2 * j2 + 1], a1);
  }
}

// ---------------- head: sigmoid((mean @ W1 + b1) @ W2 + b2), bounds inline ----------------
__global__ __launch_bounds__(128) void k_head(const float* __restrict__ pooled,
                                              const int* __restrict__ batch, int N,
                                              const float* __restrict__ w1,
                                              const float* __restrict__ b1,
                                              const float* __restrict__ w2,
                                              const float* __restrict__ b2,
                                              float* __restrict__ out) {
  int g = blockIdx.x;
  int j = threadIdx.x;
  __shared__ float pv[H];
  __shared__ float red[H];
  __shared__ int bnd[2];
  if (j < 2) {
    int target = g + j;
    int lo = 0, hi = N;
    while (lo < hi) {
      int mid = (lo + hi) >> 1;
      if (batch[mid] < target) lo = mid + 1;
      else hi = mid;
    }
    bnd[j] = lo;
  }
  __syncthreads();
  float c = (float)max(bnd[1] - bnd[0], 1);
  pv[j] = pooled[g * H + j] / c;
  __syncthreads();
  float t1 = b1[j];
  #pragma unroll 4
  for (int k = 0; k < H; k++) t1 = fmaf(pv[k], w1[k * H + j], t1);
  red[j] = t1 * w2[j];
  __syncthreads();
  if (j < 64) {
    float s = red[j] + red[j + 64];
    #pragma unroll
    for (int o = 32; o; o >>= 1) s += __shfl_down(s, o);
    if (j == 0) out[g] = 1.f / (1.f + expf(-(s + b2[0])));
  }
}

extern "C" void kernel_launch(void* const* d_in, const int* in_sizes, int n_in,
                              void* d_out, int out_size, void* d_ws, size_t ws_size,
                              hipStream_t stream) {
  const float* x = (const float*)d_in[0];
  const int* eidx = (const int*)d_in[1];
  const float* ew = (const float*)d_in[2];
  const int* batch = (const int*)d_in[3];
  const float* conv_ws = (const float*)d_in[4];  // [5][4][128][128]
  const float* conv_bs = (const float*)d_in[5];  // [5][128]
  const float* lin1_w = (const float*)d_in[6];
  const float* lin1_b = (const float*)d_in[7];
  const float* lin2_w = (const float*)d_in[8];
  const float* lin2_b = (const float*)d_in[9];
  float* out = (float*)d_out;

  const int N = in_sizes[0] / H;  // 50000
  const int E = in_sizes[2];      // 800000
  const int* row = eidx;
  const int* col = eidx + E;

  char* p = (char*)d_ws;
  auto alloc = [&](size_t bytes) {
    char* q = p;
    p += (bytes + 255) & ~(size_t)255;
    return q;
  };
  int* cnt = (int*)alloc((size_t)N * 4);
  int* ptrb = (int*)alloc((size_t)(N + 1) * 4);
  int* rank = (int*)alloc((size_t)E * 4);
  float* dis = (float*)alloc((size_t)N * 4);
  int2* es = (int2*)alloc((size_t)E * 8);
  unsigned char* x8 = (unsigned char*)alloc((size_t)N * H);
  unsigned char* C0 = (unsigned char*)alloc((size_t)N * H);
  unsigned char* C1 = (unsigned char*)alloc((size_t)N * H);
  unsigned char* C2 = (unsigned char*)alloc((size_t)N * H);
  unsigned char* C3 = (unsigned char*)alloc((size_t)N * H);
  unsigned char* W8 = (unsigned char*)alloc((size_t)5 * H * 512);
  int* bsum = (int*)alloc(256 * 4);
  int* boff = (int*)alloc(256 * 4);
  float* pooled = (float*)alloc((size_t)NGRAPH * H * 4);

  hipMemsetAsync(cnt, 0, (size_t)N * 4, stream);
  hipMemsetAsync(pooled, 0, (size_t)NGRAPH * H * 4, stream);

  int eb = (E + 255) / 256;
  int nb = (N + 255) / 256;   // 196 <= 256
  k_cvt_x<<<(N * H / 4 + 255) / 256, 256, 0, stream>>>(x, x8, N * H / 4);
  k_cvt_w<<<(5 * H * 512 / 4 + 255) / 256, 256, 0, stream>>>(conv_ws, W8, 5 * H * 512 / 4);
  k_count<<<eb, 256, 0, stream>>>(col, cnt, rank, E);
  k_scan1<<<nb, 256, 0, stream>>>(cnt, bsum, N);
  k_scan2<<<1, 256, 0, stream>>>(bsum, boff, nb);
  k_scan3<<<nb, 256, 0, stream>>>(cnt, boff, ptrb, N);
  k_scatter<<<eb, 256, 0, stream>>>(row, col, ew, ptrb, rank, es, E);
  k_degnorm1<<<nb, 256, 0, stream>>>(ptrb, es, dis, N);
  k_degnorm2<<<nb, 256, 0, stream>>>(ptrb, es, dis, N);

  int gemm_blocks = (N + 127) / 128;
  int prop_blocks = (N + 3) / 4;  // 4 waves (nodes) per 256-thread block

  const unsigned char* P8 = x8;
  for (int layer = 0; layer < 5; layer++) {
    const unsigned char* Wl = W8 + (size_t)layer * H * 512;
    const float* bl = conv_bs + (size_t)layer * H;
    k_prop<<<prop_blocks, 256, 0, stream>>>(P8, C0, ptrb, es, N);
    k_prop<<<prop_blocks, 256, 0, stream>>>(C0, C1, ptrb, es, N);
    k_prop<<<prop_blocks, 256, 0, stream>>>(C1, C2, ptrb, es, N);
    // O8=C3 aliases P8 for layers>=1: each block reads only its own 128 rows of
    // X0 (during staging) and writes those same rows only in the epilogue -> safe.
    k_fgemm<<<gemm_blocks, 256, 0, stream>>>(P8, C0, C1, C2, Wl, bl, C3, N);
    P8 = C3;
  }

  k_pool<<<(N + POOL_ROWS - 1) / POOL_ROWS, 256, 0, stream>>>(P8, batch, pooled, N);
  k_head<<<NGRAPH, 128, 0, stream>>>(pooled, batch, N, lin1_w, lin1_b, lin2_w, lin2_b, out);
}

// Round 7
// 481.128 us; speedup vs baseline: 4.2161x; 1.1951x over previous
//
#include <hip/hip_runtime.h>
#include <math.h>

#define H 128
#define NGRAPH 64

using f32x4 = __attribute__((ext_vector_type(4))) float;
using f32x2 = __attribute__((ext_vector_type(2))) float;

__device__ inline float bf2f(ushort u) {
  unsigned int b = ((unsigned int)u) << 16;
  return __builtin_bit_cast(float, b);
}
__device__ inline ushort f2bf(float f) {
  unsigned int u = __builtin_bit_cast(unsigned int, f);
  u = (u + 0x7FFF + ((u >> 16) & 1)) >> 16;  // RNE
  return (ushort)u;
}

// accumulate 8 fp8 channels (uint2) scaled by n into acc[8]
#define ACC8(accv, v, n)                                                                     \
  {                                                                                          \
    f32x2 c;                                                                                 \
    c = __builtin_amdgcn_cvt_pk_f32_fp8((v).x, false);                                       \
    accv[0] = fmaf(n, c[0], accv[0]); accv[1] = fmaf(n, c[1], accv[1]);                      \
    c = __builtin_amdgcn_cvt_pk_f32_fp8((v).x, true);                                        \
    accv[2] = fmaf(n, c[0], accv[2]); accv[3] = fmaf(n, c[1], accv[3]);                      \
    c = __builtin_amdgcn_cvt_pk_f32_fp8((v).y, false);                                       \
    accv[4] = fmaf(n, c[0], accv[4]); accv[5] = fmaf(n, c[1], accv[5]);                      \
    c = __builtin_amdgcn_cvt_pk_f32_fp8((v).y, true);                                        \
    accv[6] = fmaf(n, c[0], accv[6]); accv[7] = fmaf(n, c[1], accv[7]);                      \
  }

// ---------------- x fp32 -> fp8 ----------------
__global__ __launch_bounds__(256) void k_cvt_x(const float* __restrict__ x,
                                               unsigned char* __restrict__ x8, int total4) {
  int i = blockIdx.x * blockDim.x + threadIdx.x;
  if (i >= total4) return;
  float4 v = *(const float4*)(x + (size_t)i * 4);
  int p = __builtin_amdgcn_cvt_pk_fp8_f32(v.x, v.y, 0, false);
  p = __builtin_amdgcn_cvt_pk_fp8_f32(v.z, v.w, p, true);
  *(unsigned int*)(x8 + (size_t)i * 4) = (unsigned int)p;
}

// ---------------- transpose+convert weights to fp8: W8[l][j][k] = W[l][k/128][k%128][j] ----
__global__ __launch_bounds__(256) void k_cvt_w(const float* __restrict__ w,
                                               unsigned char* __restrict__ w8, int total4) {
  int i = blockIdx.x * blockDim.x + threadIdx.x;
  if (i >= total4) return;          // total4 = 5*128*512/4
  int f = i * 4;
  int l = f >> 16;
  int j = (f >> 9) & 127;
  int k = f & 511;                  // k..k+3 stay within one q (4 | 128)
  int q = k >> 7, kk = k & 127;
  const float* src = w + (((size_t)(l * 4 + q) * H + kk) * H + j);
  float v0 = src[0], v1 = src[H], v2 = src[2 * H], v3 = src[3 * H];
  int p = __builtin_amdgcn_cvt_pk_fp8_f32(v0, v1, 0, false);
  p = __builtin_amdgcn_cvt_pk_fp8_f32(v2, v3, p, true);
  *(unsigned int*)(w8 + f) = (unsigned int)p;
}

// ---------------- count: rank[e] = old cnt[col[e]]++ (the ONLY atomic pass) ----------------
__global__ void k_count(const int* __restrict__ col, int* __restrict__ cnt,
                        int* __restrict__ rank, int E) {
  int e = blockIdx.x * blockDim.x + threadIdx.x;
  if (e < E) rank[e] = atomicAdd(&cnt[col[e]], 1);
}

// ---------------- parallel 3-phase exclusive scan ----------------
__global__ __launch_bounds__(256) void k_scan1(const int* __restrict__ cnt,
                                               int* __restrict__ bsum, int N) {
  int i = blockIdx.x * 256 + threadIdx.x;
  int v = (i < N) ? cnt[i] : 0;
  __shared__ int red[256];
  red[threadIdx.x] = v;
  __syncthreads();
  #pragma unroll
  for (int o = 128; o; o >>= 1) {
    if (threadIdx.x < o) red[threadIdx.x] += red[threadIdx.x + o];
    __syncthreads();
  }
  if (threadIdx.x == 0) bsum[blockIdx.x] = red[0];
}

__global__ __launch_bounds__(256) void k_scan2(const int* __restrict__ bsum,
                                               int* __restrict__ boff, int nb) {
  __shared__ int s[256];
  int t = threadIdx.x;
  int v = (t < nb) ? bsum[t] : 0;
  s[t] = v;
  __syncthreads();
  #pragma unroll
  for (int d = 1; d < 256; d <<= 1) {
    int u = (t >= d) ? s[t - d] : 0;
    __syncthreads();
    s[t] += u;
    __syncthreads();
  }
  if (t < nb) boff[t] = s[t] - v;  // exclusive prefix
}

__global__ __launch_bounds__(256) void k_scan3(const int* __restrict__ cnt,
                                               const int* __restrict__ boff,
                                               int* __restrict__ ptr, int N) {
  int t = threadIdx.x;
  int i = blockIdx.x * 256 + t;
  int v = (i < N) ? cnt[i] : 0;
  __shared__ int s[256];
  s[t] = v;
  __syncthreads();
  #pragma unroll
  for (int d = 1; d < 256; d <<= 1) {
    int u = (t >= d) ? s[t - d] : 0;
    __syncthreads();
    s[t] += u;
    __syncthreads();
  }
  int ex = boff[blockIdx.x] + s[t] - v;
  if (i < N) {
    ptr[i] = ex;
    if (i == N - 1) ptr[N] = ex + v;
  }
}

// ---------------- scatter packed (row:u16 | w:bf16) into CSC order — NO atomics ----------------
__global__ void k_scatter(const int* __restrict__ row, const int* __restrict__ col,
                          const float* __restrict__ w, const int* __restrict__ ptr,
                          const int* __restrict__ rank, unsigned int* __restrict__ es, int E) {
  int e = blockIdx.x * blockDim.x + threadIdx.x;
  if (e < E) {
    int pos = ptr[col[e]] + rank[e];
    es[pos] = ((unsigned int)row[e] & 0xFFFFu) | ((unsigned int)f2bf(w[e]) << 16);
  }
}

// ---------------- per-node degree -> dis = rsqrt(deg) ----------------
__global__ __launch_bounds__(256) void k_degnorm1(const int* __restrict__ ptr,
                                                  const unsigned int* __restrict__ es,
                                                  float* __restrict__ dis, int N) {
  int v = blockIdx.x * blockDim.x + threadIdx.x;
  if (v >= N) return;
  int s = ptr[v], e = ptr[v + 1];
  float d = 0.f;
  for (int i = s; i < e; i++) d += bf2f((ushort)(es[i] >> 16));
  dis[v] = d > 0.f ? rsqrtf(d) : 0.f;
}

// ---------------- per-edge norm: es.hi = bf16(dis[row]*w*dis[col]) ----------------
__global__ __launch_bounds__(256) void k_degnorm2(const int* __restrict__ ptr,
                                                  unsigned int* __restrict__ es,
                                                  const float* __restrict__ dis, int N) {
  int v = blockIdx.x * blockDim.x + threadIdx.x;
  if (v >= N) return;
  int s = ptr[v], e = ptr[v + 1];
  float dv = dis[v];
  for (int i = s; i < e; i++) {
    unsigned int u = es[i];
    float nm = dis[u & 0xFFFFu] * bf2f((ushort)(u >> 16)) * dv;
    es[i] = (u & 0xFFFFu) | ((unsigned int)f2bf(nm) << 16);
  }
}

// ---------------- propagation: fp8 gather, fp32 accumulate, fp8 write ----------------
// one 16-lane group per dst node (4 nodes/wave); lane owns 8 channels end-to-end;
// 4-deep unrolled gather pipeline (4 x 128B rows in flight per group), no cross-lane reduce.
__global__ __launch_bounds__(256) void k_prop(const unsigned char* __restrict__ hin8,
                                              unsigned char* __restrict__ hout8,
                                              const int* __restrict__ ptr,
                                              const unsigned int* __restrict__ es, int N) {
  int node = (blockIdx.x * 256 + threadIdx.x) >> 4;
  if (node >= N) return;
  int l15 = threadIdx.x & 15;  // channel block: 8 fp8 at byte l15*8
  int s = ptr[node], e = ptr[node + 1];
  float a[8] = {0.f, 0.f, 0.f, 0.f, 0.f, 0.f, 0.f, 0.f};
  float b[8] = {0.f, 0.f, 0.f, 0.f, 0.f, 0.f, 0.f, 0.f};
  const unsigned char* base = hin8 + l15 * 8;
  int i = s;
  for (; i + 3 < e; i += 4) {
    unsigned int u0 = es[i], u1 = es[i + 1], u2 = es[i + 2], u3 = es[i + 3];
    uint2 v0 = *(const uint2*)(base + (size_t)(u0 & 0xFFFFu) * H);
    uint2 v1 = *(const uint2*)(base + (size_t)(u1 & 0xFFFFu) * H);
    uint2 v2 = *(const uint2*)(base + (size_t)(u2 & 0xFFFFu) * H);
    uint2 v3 = *(const uint2*)(base + (size_t)(u3 & 0xFFFFu) * H);
    float n0 = bf2f((ushort)(u0 >> 16));
    float n1 = bf2f((ushort)(u1 >> 16));
    float n2 = bf2f((ushort)(u2 >> 16));
    float n3 = bf2f((ushort)(u3 >> 16));
    ACC8(a, v0, n0);
    ACC8(b, v1, n1);
    ACC8(a, v2, n2);
    ACC8(b, v3, n3);
  }
  for (; i < e; i++) {
    unsigned int u0 = es[i];
    uint2 v0 = *(const uint2*)(base + (size_t)(u0 & 0xFFFFu) * H);
    float n0 = bf2f((ushort)(u0 >> 16));
    ACC8(a, v0, n0);
  }
  #pragma unroll
  for (int j = 0; j < 8; j++) a[j] += b[j];
  int p0 = __builtin_amdgcn_cvt_pk_fp8_f32(a[0], a[1], 0, false);
  p0 = __builtin_amdgcn_cvt_pk_fp8_f32(a[2], a[3], p0, true);
  int p1 = __builtin_amdgcn_cvt_pk_fp8_f32(a[4], a[5], 0, false);
  p1 = __builtin_amdgcn_cvt_pk_fp8_f32(a[6], a[7], p1, true);
  *(uint2*)(hout8 + (size_t)node * H + l15 * 8) = make_uint2((unsigned int)p0, (unsigned int)p1);
}

// ---------------- fused TAGConv GEMM (fp8 MFMA): O8 = relu([X0|X1|X2|X3] @ Wcat + b) ----
__global__ __launch_bounds__(256) void k_fgemm(const unsigned char* __restrict__ X0,
                                               const unsigned char* __restrict__ X1,
                                               const unsigned char* __restrict__ X2,
                                               const unsigned char* __restrict__ X3,
                                               const unsigned char* __restrict__ W8,  // [128][512] fp8 (j-major)
                                               const float* __restrict__ bias,
                                               unsigned char* __restrict__ O8, int N) {
  __shared__ unsigned char As[128][72];
  __shared__ unsigned char Bs[128][72];
  int t = threadIdx.x;
  int r0 = blockIdx.x * 128;
  int w = t >> 6, lane = t & 63;
  int mw = w >> 1, nw = w & 1;
  int l15 = lane & 15, l4 = lane >> 4;

  f32x4 acc[4][4];
  #pragma unroll
  for (int i = 0; i < 4; i++)
    #pragma unroll
    for (int j = 0; j < 4; j++) acc[i][j] = (f32x4){0.f, 0.f, 0.f, 0.f};

  for (int it = 0; it < 8; ++it) {
    const unsigned char* Xp = (it < 2) ? X0 : (it < 4) ? X1 : (it < 6) ? X2 : X3;
    int kb = (it & 1) * 64;
    int k0 = it * 64;
    #pragma unroll
    for (int p = 0; p < 2; p++) {
      int idx = t + p * 256;          // 0..511
      int rj = idx >> 2;              // 0..127
      int kc = (idx & 3) << 4;        // 0,16,32,48
      int gr = r0 + rj;
      uint4 av = make_uint4(0, 0, 0, 0);
      if (gr < N) av = *(const uint4*)(Xp + (size_t)gr * H + kb + kc);
      *(uint4*)&As[rj][kc] = av;
      *(uint4*)&Bs[rj][kc] = *(const uint4*)(W8 + (size_t)rj * 512 + k0 + kc);
    }
    __syncthreads();
    #pragma unroll
    for (int ks = 0; ks < 2; ks++) {
      int kk = ks * 32 + l4 * 8;
      long a[4], b[4];
      #pragma unroll
      for (int mf = 0; mf < 4; mf++) a[mf] = *(const long*)&As[mw * 64 + mf * 16 + l15][kk];
      #pragma unroll
      for (int nf = 0; nf < 4; nf++) b[nf] = *(const long*)&Bs[nw * 64 + nf * 16 + l15][kk];
      #pragma unroll
      for (int mf = 0; mf < 4; mf++)
        #pragma unroll
        for (int nf = 0; nf < 4; nf++)
          acc[mf][nf] = __builtin_amdgcn_mfma_f32_16x16x32_fp8_fp8(a[mf], b[nf], acc[mf][nf], 0, 0, 0);
    }
    __syncthreads();
  }

  #pragma unroll
  for (int nf = 0; nf < 4; nf++) {
    int colj = nw * 64 + nf * 16 + l15;
    float bv = bias[colj];
    #pragma unroll
    for (int mf = 0; mf < 4; mf++) {
      int rbase = r0 + mw * 64 + mf * 16 + l4 * 4;
      #pragma unroll
      for (int r = 0; r < 4; r++) {
        int rr = rbase + r;
        if (rr < N) {
          float v = fmaxf(acc[mf][nf][r] + bv, 0.f);
          O8[(size_t)rr * H + colj] =
              (unsigned char)(__builtin_amdgcn_cvt_pk_fp8_f32(v, v, 0, false) & 0xFF);
        }
      }
    }
  }
}

// ---------------- global mean pool (fp8 in): parallel atomic sums ----------------
#define POOL_ROWS 64
__global__ __launch_bounds__(256) void k_pool(const unsigned char* __restrict__ h8,
                                              const int* __restrict__ batch,
                                              float* __restrict__ pooled, int N) {
  int r0 = blockIdx.x * POOL_ROWS;
  int j2 = threadIdx.x & 63;   // channel pair: channels 2*j2, 2*j2+1
  int q = threadIdx.x >> 6;    // 0..3: row subset
  int rend = min(r0 + POOL_ROWS, N);
  float a0 = 0.f, a1 = 0.f;
  int cur = -1;
  for (int r = r0 + q; r < rend; r += 4) {
    int g = batch[r];
    if (g != cur) {
      if (cur >= 0) {
        atomicAdd(&pooled[cur * H + 2 * j2], a0);
        atomicAdd(&pooled[cur * H + 2 * j2 + 1], a1);
      }
      cur = g;
      a0 = a1 = 0.f;
    }
    unsigned int v = *(const ushort*)(h8 + (size_t)r * H + 2 * j2);
    f32x2 c = __builtin_amdgcn_cvt_pk_f32_fp8(v, false);
    a0 += c[0];
    a1 += c[1];
  }
  if (cur >= 0) {
    atomicAdd(&pooled[cur * H + 2 * j2], a0);
    atomicAdd(&pooled[cur * H + 2 * j2 + 1], a1);
  }
}

// ---------------- head: sigmoid((mean @ W1 + b1) @ W2 + b2), bounds inline ----------------
__global__ __launch_bounds__(128) void k_head(const float* __restrict__ pooled,
                                              const int* __restrict__ batch, int N,
                                              const float* __restrict__ w1,
                                              const float* __restrict__ b1,
                                              const float* __restrict__ w2,
                                              const float* __restrict__ b2,
                                              float* __restrict__ out) {
  int g = blockIdx.x;
  int j = threadIdx.x;
  __shared__ float pv[H];
  __shared__ float red[H];
  __shared__ int bnd[2];
  if (j < 2) {
    int target = g + j;
    int lo = 0, hi = N;
    while (lo < hi) {
      int mid = (lo + hi) >> 1;
      if (batch[mid] < target) lo = mid + 1;
      else hi = mid;
    }
    bnd[j] = lo;
  }
  __syncthreads();
  float c = (float)max(bnd[1] - bnd[0], 1);
  pv[j] = pooled[g * H + j] / c;
  __syncthreads();
  float t1 = b1[j];
  #pragma unroll 4
  for (int k = 0; k < H; k++) t1 = fmaf(pv[k], w1[k * H + j], t1);
  red[j] = t1 * w2[j];
  __syncthreads();
  if (j < 64) {
    float s = red[j] + red[j + 64];
    #pragma unroll
    for (int o = 32; o; o >>= 1) s += __shfl_down(s, o);
    if (j == 0) out[g] = 1.f / (1.f + expf(-(s + b2[0])));
  }
}

extern "C" void kernel_launch(void* const* d_in, const int* in_sizes, int n_in,
                              void* d_out, int out_size, void* d_ws, size_t ws_size,
                              hipStream_t stream) {
  const float* x = (const float*)d_in[0];
  const int* eidx = (const int*)d_in[1];
  const float* ew = (const float*)d_in[2];
  const int* batch = (const int*)d_in[3];
  const float* conv_ws = (const float*)d_in[4];  // [5][4][128][128]
  const float* conv_bs = (const float*)d_in[5];  // [5][128]
  const float* lin1_w = (const float*)d_in[6];
  const float* lin1_b = (const float*)d_in[7];
  const float* lin2_w = (const float*)d_in[8];
  const float* lin2_b = (const float*)d_in[9];
  float* out = (float*)d_out;

  const int N = in_sizes[0] / H;  // 50000  (row packing assumes N <= 65535)
  const int E = in_sizes[2];      // 800000
  const int* row = eidx;
  const int* col = eidx + E;

  char* p = (char*)d_ws;
  auto alloc = [&](size_t bytes) {
    char* q = p;
    p += (bytes + 255) & ~(size_t)255;
    return q;
  };
  int* cnt = (int*)alloc((size_t)N * 4);
  int* ptrb = (int*)alloc((size_t)(N + 1) * 4);
  int* rank = (int*)alloc((size_t)E * 4);
  float* dis = (float*)alloc((size_t)N * 4);
  unsigned int* es = (unsigned int*)alloc((size_t)E * 4);
  unsigned char* x8 = (unsigned char*)alloc((size_t)N * H);
  unsigned char* C0 = (unsigned char*)alloc((size_t)N * H);
  unsigned char* C1 = (unsigned char*)alloc((size_t)N * H);
  unsigned char* C2 = (unsigned char*)alloc((size_t)N * H);
  unsigned char* C3 = (unsigned char*)alloc((size_t)N * H);
  unsigned char* W8 = (unsigned char*)alloc((size_t)5 * H * 512);
  int* bsum = (int*)alloc(256 * 4);
  int* boff = (int*)alloc(256 * 4);
  float* pooled = (float*)alloc((size_t)NGRAPH * H * 4);

  hipMemsetAsync(cnt, 0, (size_t)N * 4, stream);
  hipMemsetAsync(pooled, 0, (size_t)NGRAPH * H * 4, stream);

  int eb = (E + 255) / 256;
  int nb = (N + 255) / 256;   // 196 <= 256
  k_cvt_x<<<(N * H / 4 + 255) / 256, 256, 0, stream>>>(x, x8, N * H / 4);
  k_cvt_w<<<(5 * H * 512 / 4 + 255) / 256, 256, 0, stream>>>(conv_ws, W8, 5 * H * 512 / 4);
  k_count<<<eb, 256, 0, stream>>>(col, cnt, rank, E);
  k_scan1<<<nb, 256, 0, stream>>>(cnt, bsum, N);
  k_scan2<<<1, 256, 0, stream>>>(bsum, boff, nb);
  k_scan3<<<nb, 256, 0, stream>>>(cnt, boff, ptrb, N);
  k_scatter<<<eb, 256, 0, stream>>>(row, col, ew, ptrb, rank, es, E);
  k_degnorm1<<<nb, 256, 0, stream>>>(ptrb, es, dis, N);
  k_degnorm2<<<nb, 256, 0, stream>>>(ptrb, es, dis, N);

  int gemm_blocks = (N + 127) / 128;
  int prop_blocks = (N + 15) / 16;  // 16 nodes per 256-thread block (16 lanes/node)

  const unsigned char* P8 = x8;
  for (int layer = 0; layer < 5; layer++) {
    const unsigned char* Wl = W8 + (size_t)layer * H * 512;
    const float* bl = conv_bs + (size_t)layer * H;
    k_prop<<<prop_blocks, 256, 0, stream>>>(P8, C0, ptrb, es, N);
    k_prop<<<prop_blocks, 256, 0, stream>>>(C0, C1, ptrb, es, N);
    k_prop<<<prop_blocks, 256, 0, stream>>>(C1, C2, ptrb, es, N);
    // O8=C3 aliases P8 for layers>=1: each block reads only its own 128 rows of
    // X0 (during staging) and writes those same rows only in the epilogue -> safe.
    k_fgemm<<<gemm_blocks, 256, 0, stream>>>(P8, C0, C1, C2, Wl, bl, C3, N);
    P8 = C3;
  }

  k_pool<<<(N + POOL_ROWS - 1) / POOL_ROWS, 256, 0, stream>>>(P8, batch, pooled, N);
  k_head<<<NGRAPH, 128, 0, stream>>>(pooled, batch, N, lin1_w, lin1_b, lin2_w, lin2_b, out);
}